// Round 1
// baseline (4254.425 us; speedup 1.0000x reference)
//
#include <hip/hip_runtime.h>

#define B_ 8
#define C_ 129
#define P_ 62
#define L_ 20
#define D_ 256
#define NSEG (B_*C_*P_)   /* 63984 */
#define N2   (B_*P_)      /* 496 */
#define SEGS 4

__device__ __forceinline__ float gelu_f(float x) {
    return 0.5f * x * (1.0f + erff(x * 0.7071067811865476f));
}

// ---------------- prep: weight transposes ----------------
__global__ void prep_kernel(const float* __restrict__ w2, const float* __restrict__ w3,
                            const float* __restrict__ mw, const float* __restrict__ pw,
                            float* __restrict__ w2T, float* __restrict__ w3T,
                            float* __restrict__ mwT, float* __restrict__ pwT) {
    int idx = blockIdx.x * blockDim.x + threadIdx.x;
    int stride = gridDim.x * blockDim.x;
    // w2T[(ci*3+k)*128 + co] = w2[(co*64+ci)*3 + k]
    for (int j = idx; j < 128*64*3; j += stride) {
        int co = j & 127; int rest = j >> 7; int k = rest % 3; int ci = rest / 3;
        w2T[j] = w2[(co*64 + ci)*3 + k];
    }
    // w3T[(ci*3+k)*256 + co] = w3[(co*128+ci)*3 + k]
    for (int j = idx; j < 256*128*3; j += stride) {
        int co = j & 255; int rest = j >> 8; int k = rest % 3; int ci = rest / 3;
        w3T[j] = w3[(co*128 + ci)*3 + k];
    }
    // mwT[c*132 + o] = mw[o*129 + c]
    for (int j = idx; j < 129*129; j += stride) {
        int c = j / 129, o = j % 129;
        mwT[c*132 + o] = mw[o*129 + c];
    }
    // pwT[d*256 + e] = pw[e*256 + d]
    for (int j = idx; j < 256*256; j += stride) {
        int d = j >> 8, e = j & 255;
        pwT[j] = pw[e*256 + d];
    }
}

// ---------------- kernel 1: conv stack ----------------
__global__ __launch_bounds__(256) void conv_stack_kernel(
    const float* __restrict__ x,
    const float* __restrict__ w1, const float* __restrict__ b1,
    const float* __restrict__ w2T, const float* __restrict__ b2,
    const float* __restrict__ w3T, const float* __restrict__ b3,
    float* __restrict__ feat)
{
    __shared__ float xs[SEGS][22];        // padded: [0]=0, [1..20]=x, [21]=0
    __shared__ float h1[SEGS][64][22];    // padded rows
    __shared__ float hp[SEGS][128][12];   // padded rows (pool output, len 10)
    int t = threadIdx.x;
    int seg0 = blockIdx.x * SEGS;

    if (t < SEGS*22) {
        int s = t / 22, i = t % 22;
        float v = 0.f;
        if (i >= 1 && i <= L_) v = x[(seg0 + s)*L_ + (i-1)];
        xs[s][i] = v;
    }
    __syncthreads();

    // ---- conv1: 1 -> 64, L=20 ----
    {
        int co = t & 63, grp = t >> 6;
        float ww0 = w1[co*3+0], ww1 = w1[co*3+1], ww2 = w1[co*3+2];
        float bb = b1[co];
        for (int s = 0; s < SEGS; ++s) {
            #pragma unroll
            for (int i = 0; i < 5; ++i) {
                int l = grp*5 + i;
                float v = xs[s][l]*ww0 + xs[s][l+1]*ww1 + xs[s][l+2]*ww2 + bb;
                h1[s][co][1+l] = gelu_f(v);
            }
            if (grp == 0) h1[s][co][0]  = 0.f;
            if (grp == 3) h1[s][co][21] = 0.f;
        }
    }
    __syncthreads();

    // ---- conv2: 64 -> 128, L=20, then gelu+maxpool2 -> len 10 ----
    {
        int co = t & 127, half = t >> 7;
        int l0 = half * 10;
        float acc[SEGS][10];
        #pragma unroll
        for (int s = 0; s < SEGS; ++s)
            #pragma unroll
            for (int i = 0; i < 10; ++i) acc[s][i] = 0.f;

        for (int ci = 0; ci < 64; ++ci) {
            float ww0 = w2T[(ci*3+0)*128 + co];
            float ww1 = w2T[(ci*3+1)*128 + co];
            float ww2 = w2T[(ci*3+2)*128 + co];
            #pragma unroll
            for (int s = 0; s < SEGS; ++s) {
                float r[12];
                const float2* src = (const float2*)&h1[s][ci][l0];
                #pragma unroll
                for (int q = 0; q < 6; ++q) { float2 v = src[q]; r[2*q] = v.x; r[2*q+1] = v.y; }
                #pragma unroll
                for (int i = 0; i < 10; ++i)
                    acc[s][i] += r[i]*ww0 + r[i+1]*ww1 + r[i+2]*ww2;
            }
        }
        float bb = b2[co];
        #pragma unroll
        for (int s = 0; s < SEGS; ++s) {
            #pragma unroll
            for (int j = 0; j < 5; ++j) {
                float a0 = gelu_f(acc[s][2*j]   + bb);
                float a1 = gelu_f(acc[s][2*j+1] + bb);
                hp[s][co][1 + half*5 + j] = fmaxf(a0, a1);
            }
            if (half == 0) hp[s][co][0]  = 0.f;
            else           hp[s][co][11] = 0.f;
        }
    }
    __syncthreads();

    // ---- conv3: 128 -> 256, len 10, gelu, mean ----
    {
        int co = t;
        float acc[SEGS][10];
        #pragma unroll
        for (int s = 0; s < SEGS; ++s)
            #pragma unroll
            for (int j = 0; j < 10; ++j) acc[s][j] = 0.f;

        for (int ci = 0; ci < 128; ++ci) {
            float ww0 = w3T[(ci*3+0)*256 + co];
            float ww1 = w3T[(ci*3+1)*256 + co];
            float ww2 = w3T[(ci*3+2)*256 + co];
            #pragma unroll
            for (int s = 0; s < SEGS; ++s) {
                float r[12];
                const float2* src = (const float2*)&hp[s][ci][0];
                #pragma unroll
                for (int q = 0; q < 6; ++q) { float2 v = src[q]; r[2*q] = v.x; r[2*q+1] = v.y; }
                #pragma unroll
                for (int j = 0; j < 10; ++j)
                    acc[s][j] += r[j]*ww0 + r[j+1]*ww1 + r[j+2]*ww2;
            }
        }
        float bb = b3[co];
        for (int s = 0; s < SEGS; ++s) {
            float sum = 0.f;
            #pragma unroll
            for (int j = 0; j < 10; ++j) sum += gelu_f(acc[s][j] + bb);
            int seg = seg0 + s;
            int b = seg / (C_*P_);
            int rem = seg % (C_*P_);
            int c = rem / P_;
            int p = rem % P_;
            feat[(((b*P_ + p)*C_) + c)*D_ + co] = sum * 0.1f;
        }
    }
}

// ---------------- kernel 2: channel mix + gelu + layernorm ----------------
__global__ __launch_bounds__(256) void mix_ln_kernel(
    const float* __restrict__ feat, const float* __restrict__ mwT,
    const float* __restrict__ mix_b, const float* __restrict__ ln_w,
    const float* __restrict__ ln_b, float* __restrict__ mbuf)
{
    __shared__ float ts[4][132];
    int t = threadIdx.x;
    int n2 = blockIdx.x >> 6;
    int d0 = (blockIdx.x & 63) * 4;

    for (int idx = t; idx < 4*C_; idx += 256) {
        int w = idx & 3, c = idx >> 2;
        ts[w][c] = feat[(n2*C_ + c)*D_ + d0 + w];
    }
    __syncthreads();

    int w = t >> 6, lane = t & 63;
    int d = d0 + w;
    int o0 = lane*2;
    float a0 = 0.f, a1 = 0.f, a2 = 0.f;
    for (int c = 0; c < C_; ++c) {
        float tv = ts[w][c];
        float2 mw2 = *(const float2*)&mwT[c*132 + o0];
        a0 += tv * mw2.x;
        a1 += tv * mw2.y;
        a2 += tv * mwT[c*132 + 128];
    }
    a0 += mix_b[o0]; a1 += mix_b[o0+1]; a2 += mix_b[128];
    float m0 = gelu_f(a0), m1 = gelu_f(a1), m2 = gelu_f(a2);

    float sm = m0 + m1, sq = m0*m0 + m1*m1;
    #pragma unroll
    for (int off = 32; off; off >>= 1) {
        sm += __shfl_xor(sm, off);
        sq += __shfl_xor(sq, off);
    }
    float total = sm + m2;        // o=128 counted once
    float qt    = sq + m2*m2;
    float mu  = total * (1.f/129.f);
    float var = qt * (1.f/129.f) - mu*mu;
    float rs  = rsqrtf(var + 1e-5f);

    float y0 = (m0 - mu)*rs*ln_w[o0]   + ln_b[o0];
    float y1 = (m1 - mu)*rs*ln_w[o0+1] + ln_b[o0+1];
    float* row = &mbuf[(n2*256 + d)*130];
    *(float2*)&row[o0] = make_float2(y0, y1);
    if (lane == 0) {
        float y2 = (m2 - mu)*rs*ln_w[128] + ln_b[128];
        row[128] = y2;
    }
}

// ---------------- kernel 3: proj + output transpose ----------------
__global__ __launch_bounds__(256) void proj_kernel(
    const float* __restrict__ mbuf, const float* __restrict__ pwT,
    const float* __restrict__ proj_b, float* __restrict__ out)
{
    int bid = blockIdx.x;
    int n2 = bid / 17, cb = bid % 17;
    int t = threadIdx.x;
    int c = cb*8 + (t >> 5);
    int e = (t & 31) * 8;
    if (c >= C_) return;
    int b = n2 / P_, p = n2 % P_;

    float acc[8];
    #pragma unroll
    for (int j = 0; j < 8; ++j) acc[j] = 0.f;

    const float* mrow = &mbuf[(size_t)(n2*256)*130 + c];
    for (int d = 0; d < 256; ++d) {
        float a = mrow[d*130];
        float4 w0 = *(const float4*)&pwT[d*256 + e];
        float4 w1 = *(const float4*)&pwT[d*256 + e + 4];
        acc[0] += a*w0.x; acc[1] += a*w0.y; acc[2] += a*w0.z; acc[3] += a*w0.w;
        acc[4] += a*w1.x; acc[5] += a*w1.y; acc[6] += a*w1.z; acc[7] += a*w1.w;
    }
    float4 r0, r1;
    r0.x = acc[0] + proj_b[e+0]; r0.y = acc[1] + proj_b[e+1];
    r0.z = acc[2] + proj_b[e+2]; r0.w = acc[3] + proj_b[e+3];
    r1.x = acc[4] + proj_b[e+4]; r1.y = acc[5] + proj_b[e+5];
    r1.z = acc[6] + proj_b[e+6]; r1.w = acc[7] + proj_b[e+7];

    float* orow = &out[(((size_t)(b*C_ + c)*P_) + p)*D_ + e];
    *(float4*)&orow[0] = r0;
    *(float4*)&orow[4] = r1;
}

extern "C" void kernel_launch(void* const* d_in, const int* in_sizes, int n_in,
                              void* d_out, int out_size, void* d_ws, size_t ws_size,
                              hipStream_t stream) {
    (void)in_sizes; (void)n_in; (void)out_size; (void)ws_size;
    const float* x    = (const float*)d_in[0];
    const float* w1   = (const float*)d_in[1];
    const float* b1   = (const float*)d_in[2];
    const float* w2   = (const float*)d_in[3];
    const float* b2   = (const float*)d_in[4];
    const float* w3   = (const float*)d_in[5];
    const float* b3   = (const float*)d_in[6];
    const float* mixw = (const float*)d_in[7];
    const float* mixb = (const float*)d_in[8];
    const float* lnw  = (const float*)d_in[9];
    const float* lnb  = (const float*)d_in[10];
    const float* pw   = (const float*)d_in[11];
    const float* pb   = (const float*)d_in[12];
    float* out = (float*)d_out;
    float* ws  = (float*)d_ws;

    // workspace layout (floats)
    float* mbuf = ws;                       // 496*256*130 = 16,506,880
    float* w2T  = ws + 16506880;            // 24,576
    float* w3T  = w2T + 24576;              // 98,304
    float* mwT  = w3T + 98304;              // 129*132 = 17,028
    float* pwT  = mwT + 17028;              // 65,536  (16B-aligned)
    float* feat = out;                      // d_out reused as scratch (exactly out_size floats)

    prep_kernel<<<256, 256, 0, stream>>>(w2, w3, mixw, pw, w2T, w3T, mwT, pwT);
    conv_stack_kernel<<<NSEG/SEGS, 256, 0, stream>>>(x, w1, b1, w2T, b2, w3T, b3, feat);
    mix_ln_kernel<<<N2*64, 256, 0, stream>>>(feat, mwT, mixb, lnw, lnb, mbuf);
    proj_kernel<<<N2*17, 256, 0, stream>>>(mbuf, pwT, pb, out);
}

// Round 2
// 1562.672 us; speedup vs baseline: 2.7225x; 2.7225x over previous
//
#include <hip/hip_runtime.h>

#define B_ 8
#define C_ 129
#define P_ 62
#define L_ 20
#define D_ 256
#define NSEG (B_*C_*P_)   /* 63984 */
#define N2   (B_*P_)      /* 496 */
#define SEGB 16
#define NWG  (NSEG/SEGB)  /* 3999 */

#define S1 1416   /* h1T per-seg stride in u16: 22*64 + 8  (odd multiple of 8 u16 = 16B) */
#define S2 1544   /* hpT per-seg stride in u16: 12*128 + 8 */

typedef short short8 __attribute__((ext_vector_type(8)));
typedef float f32x4  __attribute__((ext_vector_type(4)));

__device__ __forceinline__ float gelu_f(float x) {
    return 0.5f * x * (1.0f + erff(x * 0.7071067811865476f));
}
__device__ __forceinline__ unsigned short f2bf(float f) {
    unsigned u = __float_as_uint(f);
    u = u + 0x7FFFu + ((u >> 16) & 1u);
    return (unsigned short)(u >> 16);
}

// ---------------- prep: weight transposes + MFMA fragment packing ----------------
__global__ void prep_kernel(const float* __restrict__ w2, const float* __restrict__ w3,
                            const float* __restrict__ mw, const float* __restrict__ pw,
                            float* __restrict__ mwT, float* __restrict__ pwT,
                            unsigned short* __restrict__ A2p, unsigned short* __restrict__ A3p) {
    int idx = blockIdx.x * blockDim.x + threadIdx.x;
    int stride = gridDim.x * blockDim.x;
    // mwT[c*132 + o] = mw[o*129 + c]
    for (int j = idx; j < 129*129; j += stride) {
        int c = j / 129, o = j % 129;
        mwT[c*132 + o] = mw[o*129 + c];
    }
    // pwT[d*256 + e] = pw[e*256 + d]
    for (int j = idx; j < 256*256; j += stride) {
        int d = j >> 8, e = j & 255;
        pwT[j] = pw[e*256 + d];
    }
    // A2p: conv2 weights in MFMA A-fragment order. K index = k*64+ci, kt covers
    // 32 K values: k = kt>>1, ci = (kt&1)*32 + (lane>>4)*8 + j
    for (int f = idx; f < 6*8*64*8; f += stride) {
        int j = f & 7, ln = (f >> 3) & 63, mt = (f >> 9) & 7, kt = f >> 12;
        int co = mt*16 + (ln & 15);
        int k  = kt >> 1;
        int ci = (kt & 1)*32 + (ln >> 4)*8 + j;
        A2p[f] = f2bf(w2[(co*64 + ci)*3 + k]);
    }
    // A3p: conv3 weights. K = k*128+ci, kt: k = kt>>2, ci = (kt&3)*32 + (lane>>4)*8 + j
    for (int f = idx; f < 12*16*64*8; f += stride) {
        int j = f & 7, ln = (f >> 3) & 63, mt = (f >> 9) & 15, kt = f >> 13;
        int co = mt*16 + (ln & 15);
        int k  = kt >> 2;
        int ci = (kt & 3)*32 + (ln >> 4)*8 + j;
        A3p[f] = f2bf(w3[(co*128 + ci)*3 + k]);
    }
}

// ---------------- kernel 1: conv stack via MFMA ----------------
// Per WG: 16 segments. N interleave n = position*16 + s  => one 16x16 N-tile = one position.
__global__ __launch_bounds__(512, 2) void conv_mfma_kernel(
    const float* __restrict__ x,
    const float* __restrict__ w1, const float* __restrict__ b1,
    const unsigned short* __restrict__ A2p, const float* __restrict__ b2,
    const unsigned short* __restrict__ A3p, const float* __restrict__ b3,
    float* __restrict__ feat)
{
    __shared__ __align__(16) unsigned short h1T[SEGB * S1]; // [s][l+1: 0..21][ci:64], 45312 B
    __shared__ __align__(16) unsigned short hpT[SEGB * S2]; // [s][lp+1: 0..11][co:128], 49408 B
    __shared__ float xs[SEGB][22];

    const int t = threadIdx.x;
    const int wave = t >> 6, lane = t & 63;
    const int sL = lane & 15, gL = lane >> 4;
    const int seg0 = blockIdx.x * SEGB;

    // stage x (padded)
    for (int idx = t; idx < SEGB*22; idx += 512) {
        int s = idx / 22, i = idx % 22;
        float v = 0.f;
        if (i >= 1 && i <= 20) v = x[(seg0 + s)*L_ + i - 1];
        xs[s][i] = v;
    }
    // zero pad rows (l = -1 and l = L)
    for (int idx = t; idx < SEGB*64; idx += 512) {
        int s = idx >> 6, ci = idx & 63;
        h1T[s*S1 + ci] = 0;
        h1T[s*S1 + 21*64 + ci] = 0;
    }
    for (int idx = t; idx < SEGB*128; idx += 512) {
        int s = idx >> 7, co = idx & 127;
        hpT[s*S2 + co] = 0;
        hpT[s*S2 + 11*128 + co] = 0;
    }
    __syncthreads();

    // ---- conv1: 1 -> 64, gelu, store transposed bf16 ----
    {
        int ci = t & 63, sg = t >> 6;
        float ww0 = w1[ci*3], ww1 = w1[ci*3+1], ww2 = w1[ci*3+2], bb = b1[ci];
        #pragma unroll
        for (int si = 0; si < 2; ++si) {
            int s = sg*2 + si;
            #pragma unroll
            for (int l = 0; l < 20; ++l) {
                float v = xs[s][l]*ww0 + xs[s][l+1]*ww1 + xs[s][l+2]*ww2 + bb;
                h1T[s*S1 + (l+1)*64 + ci] = f2bf(gelu_f(v));
            }
        }
    }
    __syncthreads();

    // ---- conv2 GEMM: M=128, N=320, K=192; gelu+maxpool -> hpT ----
    {
        const int mh = wave & 3, ng = wave >> 2;   // wave: 2 M-tiles, 10 l-positions
        f32x4 acc[2][10];
        #pragma unroll
        for (int mi = 0; mi < 2; ++mi)
            #pragma unroll
            for (int li = 0; li < 10; ++li) acc[mi][li] = (f32x4){0.f,0.f,0.f,0.f};

        for (int kt = 0; kt < 6; ++kt) {
            int k = kt >> 1, cih = (kt & 1) * 32;
            short8 a[2], b[10];
            #pragma unroll
            for (int mi = 0; mi < 2; ++mi)
                a[mi] = *(const short8*)(A2p + (((kt*8 + mh*2 + mi)*64 + lane) << 3));
            #pragma unroll
            for (int li = 0; li < 10; ++li) {
                int l = ng*10 + li;
                b[li] = *(short8*)&h1T[sL*S1 + (l + k)*64 + cih + gL*8];
            }
            #pragma unroll
            for (int mi = 0; mi < 2; ++mi)
                #pragma unroll
                for (int li = 0; li < 10; ++li)
                    acc[mi][li] = __builtin_amdgcn_mfma_f32_16x16x32_bf16(a[mi], b[li], acc[mi][li], 0, 0, 0);
        }
        // epilogue: +bias, gelu, pool pairs (2j,2j+1) -> hpT
        #pragma unroll
        for (int mi = 0; mi < 2; ++mi) {
            int mt = mh*2 + mi;
            int co0 = mt*16 + gL*4;
            float4 bb = *(const float4*)(b2 + co0);
            float bbr[4] = {bb.x, bb.y, bb.z, bb.w};
            #pragma unroll
            for (int j = 0; j < 5; ++j) {
                int lp = ng*5 + j;
                unsigned short pk[4];
                #pragma unroll
                for (int r = 0; r < 4; ++r) {
                    float p0 = gelu_f(acc[mi][2*j][r]   + bbr[r]);
                    float p1 = gelu_f(acc[mi][2*j+1][r] + bbr[r]);
                    pk[r] = f2bf(fmaxf(p0, p1));
                }
                *(uint2*)&hpT[sL*S2 + (lp+1)*128 + co0] = *(uint2*)pk;
            }
        }
    }
    __syncthreads();

    // ---- conv3 GEMM: M=256, N=160, K=384; gelu+mean -> feat ----
    {
        f32x4 acc[2][10];
        #pragma unroll
        for (int mi = 0; mi < 2; ++mi)
            #pragma unroll
            for (int li = 0; li < 10; ++li) acc[mi][li] = (f32x4){0.f,0.f,0.f,0.f};

        for (int kt = 0; kt < 12; ++kt) {
            int k = kt >> 2, ciq = (kt & 3) * 32;
            short8 a[2], b[10];
            #pragma unroll
            for (int mi = 0; mi < 2; ++mi)
                a[mi] = *(const short8*)(A3p + (((kt*16 + wave*2 + mi)*64 + lane) << 3));
            #pragma unroll
            for (int li = 0; li < 10; ++li)
                b[li] = *(short8*)&hpT[sL*S2 + (li + k)*128 + ciq + gL*8];
            #pragma unroll
            for (int mi = 0; mi < 2; ++mi)
                #pragma unroll
                for (int li = 0; li < 10; ++li)
                    acc[mi][li] = __builtin_amdgcn_mfma_f32_16x16x32_bf16(a[mi], b[li], acc[mi][li], 0, 0, 0);
        }
        // epilogue: +bias, gelu, mean over 10 positions, write feat[b,p,c,:]
        int seg = seg0 + sL;
        int bI = seg / (C_*P_);
        int rem = seg % (C_*P_);
        int c = rem / P_, p = rem % P_;
        float* frow = feat + (((size_t)(bI*P_ + p)*C_ + c) << 8);
        #pragma unroll
        for (int mi = 0; mi < 2; ++mi) {
            int co0 = (wave*2 + mi)*16 + gL*4;
            float4 bv = *(const float4*)(b3 + co0);
            float bbr[4] = {bv.x, bv.y, bv.z, bv.w};
            float sum[4] = {0.f, 0.f, 0.f, 0.f};
            #pragma unroll
            for (int li = 0; li < 10; ++li)
                #pragma unroll
                for (int r = 0; r < 4; ++r)
                    sum[r] += gelu_f(acc[mi][li][r] + bbr[r]);
            float4 o;
            o.x = sum[0]*0.1f; o.y = sum[1]*0.1f; o.z = sum[2]*0.1f; o.w = sum[3]*0.1f;
            *(float4*)(frow + co0) = o;
        }
    }
}

// ---------------- kernel 2: channel mix + gelu + layernorm ----------------
__global__ __launch_bounds__(256) void mix_ln_kernel(
    const float* __restrict__ feat, const float* __restrict__ mwT,
    const float* __restrict__ mix_b, const float* __restrict__ ln_w,
    const float* __restrict__ ln_b, float* __restrict__ mbuf)
{
    __shared__ float ts[4][132];
    int t = threadIdx.x;
    int n2 = blockIdx.x >> 6;
    int d0 = (blockIdx.x & 63) * 4;

    for (int idx = t; idx < 4*C_; idx += 256) {
        int w = idx & 3, c = idx >> 2;
        ts[w][c] = feat[(n2*C_ + c)*D_ + d0 + w];
    }
    __syncthreads();

    int w = t >> 6, lane = t & 63;
    int d = d0 + w;
    int o0 = lane*2;
    float a0 = 0.f, a1 = 0.f, a2 = 0.f;
    for (int c = 0; c < C_; ++c) {
        float tv = ts[w][c];
        float2 mw2 = *(const float2*)&mwT[c*132 + o0];
        a0 += tv * mw2.x;
        a1 += tv * mw2.y;
        a2 += tv * mwT[c*132 + 128];
    }
    a0 += mix_b[o0]; a1 += mix_b[o0+1]; a2 += mix_b[128];
    float m0 = gelu_f(a0), m1 = gelu_f(a1), m2 = gelu_f(a2);

    float sm = m0 + m1, sq = m0*m0 + m1*m1;
    #pragma unroll
    for (int off = 32; off; off >>= 1) {
        sm += __shfl_xor(sm, off);
        sq += __shfl_xor(sq, off);
    }
    float total = sm + m2;
    float qt    = sq + m2*m2;
    float mu  = total * (1.f/129.f);
    float var = qt * (1.f/129.f) - mu*mu;
    float rs  = rsqrtf(var + 1e-5f);

    float y0 = (m0 - mu)*rs*ln_w[o0]   + ln_b[o0];
    float y1 = (m1 - mu)*rs*ln_w[o0+1] + ln_b[o0+1];
    float* row = &mbuf[(n2*256 + d)*130];
    *(float2*)&row[o0] = make_float2(y0, y1);
    if (lane == 0) {
        float y2 = (m2 - mu)*rs*ln_w[128] + ln_b[128];
        row[128] = y2;
    }
}

// ---------------- kernel 3: proj + output transpose ----------------
__global__ __launch_bounds__(256) void proj_kernel(
    const float* __restrict__ mbuf, const float* __restrict__ pwT,
    const float* __restrict__ proj_b, float* __restrict__ out)
{
    int bid = blockIdx.x;
    int n2 = bid / 17, cb = bid % 17;
    int t = threadIdx.x;
    int c = cb*8 + (t >> 5);
    int e = (t & 31) * 8;
    if (c >= C_) return;
    int b = n2 / P_, p = n2 % P_;

    float acc[8];
    #pragma unroll
    for (int j = 0; j < 8; ++j) acc[j] = 0.f;

    const float* mrow = &mbuf[(size_t)(n2*256)*130 + c];
    for (int d = 0; d < 256; ++d) {
        float a = mrow[d*130];
        float4 w0 = *(const float4*)&pwT[d*256 + e];
        float4 w1 = *(const float4*)&pwT[d*256 + e + 4];
        acc[0] += a*w0.x; acc[1] += a*w0.y; acc[2] += a*w0.z; acc[3] += a*w0.w;
        acc[4] += a*w1.x; acc[5] += a*w1.y; acc[6] += a*w1.z; acc[7] += a*w1.w;
    }
    float4 r0, r1;
    r0.x = acc[0] + proj_b[e+0]; r0.y = acc[1] + proj_b[e+1];
    r0.z = acc[2] + proj_b[e+2]; r0.w = acc[3] + proj_b[e+3];
    r1.x = acc[4] + proj_b[e+4]; r1.y = acc[5] + proj_b[e+5];
    r1.z = acc[6] + proj_b[e+6]; r1.w = acc[7] + proj_b[e+7];

    float* orow = &out[(((size_t)(b*C_ + c)*P_) + p)*D_ + e];
    *(float4*)&orow[0] = r0;
    *(float4*)&orow[4] = r1;
}

extern "C" void kernel_launch(void* const* d_in, const int* in_sizes, int n_in,
                              void* d_out, int out_size, void* d_ws, size_t ws_size,
                              hipStream_t stream) {
    (void)in_sizes; (void)n_in; (void)out_size; (void)ws_size;
    const float* x    = (const float*)d_in[0];
    const float* w1   = (const float*)d_in[1];
    const float* b1   = (const float*)d_in[2];
    const float* w2   = (const float*)d_in[3];
    const float* b2   = (const float*)d_in[4];
    const float* w3   = (const float*)d_in[5];
    const float* b3   = (const float*)d_in[6];
    const float* mixw = (const float*)d_in[7];
    const float* mixb = (const float*)d_in[8];
    const float* lnw  = (const float*)d_in[9];
    const float* lnb  = (const float*)d_in[10];
    const float* pw   = (const float*)d_in[11];
    const float* pb   = (const float*)d_in[12];
    float* out = (float*)d_out;
    float* ws  = (float*)d_ws;

    // workspace layout (float offsets, all 16B aligned)
    float* mbuf = ws;                               // 496*256*130 = 16,506,880
    float* mwT  = ws + 16506880;                    // 129*132 = 17,028
    float* pwT  = mwT + 17028;                      // 65,536
    unsigned short* A2p = (unsigned short*)(pwT + 65536);          // 24,576 u16
    unsigned short* A3p = (unsigned short*)(pwT + 65536 + 12288);  // 98,304 u16
    float* feat = out;   // d_out reused as scratch

    prep_kernel<<<256, 256, 0, stream>>>(w2, w3, mixw, pw, mwT, pwT, A2p, A3p);
    conv_mfma_kernel<<<NWG, 512, 0, stream>>>(x, w1, b1, A2p, b2, A3p, b3, feat);
    mix_ln_kernel<<<N2*64, 256, 0, stream>>>(feat, mwT, mixb, lnw, lnb, mbuf);
    proj_kernel<<<N2*17, 256, 0, stream>>>(mbuf, pwT, pb, out);
}

// Round 3
// 662.501 us; speedup vs baseline: 6.4218x; 2.3587x over previous
//
#include <hip/hip_runtime.h>

#define B_ 8
#define C_ 129
#define P_ 62
#define L_ 20
#define D_ 256
#define NSEG (B_*C_*P_)   /* 63984 */
#define N2   (B_*P_)      /* 496 */
#define SEGB 16
#define NWG  (NSEG/SEGB)  /* 3999 */

#define S1 1416   /* h1T per-seg stride in u16 */
#define S2 1544   /* hpT per-seg stride in u16 */

#define FT_STRIDE 168   /* fT [256 d][168] u16; 16B-aligned rows, 84dw stride (2-way reads) */
#define MT_STRIDE 264   /* mT [144 o][264] u16; 132dw stride */

typedef short short8 __attribute__((ext_vector_type(8)));
typedef float f32x4  __attribute__((ext_vector_type(4)));

__device__ __forceinline__ float gelu_f(float x) {
    return 0.5f * x * (1.0f + erff(x * 0.7071067811865476f));
}
__device__ __forceinline__ unsigned short f2bf(float f) {
    unsigned u = __float_as_uint(f);
    u = u + 0x7FFFu + ((u >> 16) & 1u);
    return (unsigned short)(u >> 16);
}

// ---------------- prep: pack all weights into MFMA fragment order ----------------
__global__ void prep_kernel(const float* __restrict__ w2, const float* __restrict__ w3,
                            const float* __restrict__ mw, const float* __restrict__ pw,
                            const float* __restrict__ mixb, const float* __restrict__ lnw,
                            const float* __restrict__ lnb,
                            unsigned short* __restrict__ A2p, unsigned short* __restrict__ A3p,
                            unsigned short* __restrict__ mixA, unsigned short* __restrict__ projA,
                            float* __restrict__ bmixp, float* __restrict__ lnwp,
                            float* __restrict__ lnbp) {
    int idx = blockIdx.x * blockDim.x + threadIdx.x;
    int stride = gridDim.x * blockDim.x;
    // A2p: conv2 weights. k = kt>>1, ci = (kt&1)*32 + (lane>>4)*8 + j
    for (int f = idx; f < 6*8*64*8; f += stride) {
        int j = f & 7, ln = (f >> 3) & 63, mt = (f >> 9) & 7, kt = f >> 12;
        int co = mt*16 + (ln & 15);
        int k  = kt >> 1;
        int ci = (kt & 1)*32 + (ln >> 4)*8 + j;
        A2p[f] = f2bf(w2[(co*64 + ci)*3 + k]);
    }
    // A3p: conv3 weights. k = kt>>2, ci = (kt&3)*32 + (lane>>4)*8 + j
    for (int f = idx; f < 12*16*64*8; f += stride) {
        int j = f & 7, ln = (f >> 3) & 63, mt = (f >> 9) & 15, kt = f >> 13;
        int co = mt*16 + (ln & 15);
        int k  = kt >> 2;
        int ci = (kt & 3)*32 + (ln >> 4)*8 + j;
        A3p[f] = f2bf(w3[(co*128 + ci)*3 + k]);
    }
    // mixA: M=o (pad 144), K=c (pad 160). f = ((kt*9+mt)*64+ln)*8+j
    for (int f = idx; f < 5*9*64*8; f += stride) {
        int j = f & 7, ln = (f >> 3) & 63;
        int mt = (f >> 9) % 9, kt = (f >> 9) / 9;
        int o = mt*16 + (ln & 15);
        int c = kt*32 + (ln >> 4)*8 + j;
        mixA[f] = (o < 129 && c < 129) ? f2bf(mw[o*129 + c]) : (unsigned short)0;
    }
    // projA: M=e (256), K=d (256). f = ((kt*16+mt)*64+ln)*8+j
    for (int f = idx; f < 8*16*64*8; f += stride) {
        int j = f & 7, ln = (f >> 3) & 63, mt = (f >> 9) & 15, kt = f >> 13;
        int e = mt*16 + (ln & 15);
        int d = kt*32 + (ln >> 4)*8 + j;
        projA[f] = f2bf(pw[e*256 + d]);
    }
    // padded bias / LN tables (o < 144)
    for (int i = idx; i < 144; i += stride) {
        bmixp[i] = (i < 129) ? mixb[i] : 0.f;
        lnwp[i]  = (i < 129) ? lnw[i]  : 0.f;
        lnbp[i]  = (i < 129) ? lnb[i]  : 0.f;
    }
}

// ---------------- kernel 1: conv stack via MFMA ----------------
__global__ __launch_bounds__(512, 2) void conv_mfma_kernel(
    const float* __restrict__ x,
    const float* __restrict__ w1, const float* __restrict__ b1,
    const unsigned short* __restrict__ A2p, const float* __restrict__ b2,
    const unsigned short* __restrict__ A3p, const float* __restrict__ b3,
    float* __restrict__ feat)
{
    __shared__ __align__(16) unsigned short h1T[SEGB * S1];
    __shared__ __align__(16) unsigned short hpT[SEGB * S2];
    __shared__ float xs[SEGB][22];

    const int t = threadIdx.x;
    const int wave = t >> 6, lane = t & 63;
    const int sL = lane & 15, gL = lane >> 4;
    const int seg0 = blockIdx.x * SEGB;

    for (int idx = t; idx < SEGB*22; idx += 512) {
        int s = idx / 22, i = idx % 22;
        float v = 0.f;
        if (i >= 1 && i <= 20) v = x[(seg0 + s)*L_ + i - 1];
        xs[s][i] = v;
    }
    for (int idx = t; idx < SEGB*64; idx += 512) {
        int s = idx >> 6, ci = idx & 63;
        h1T[s*S1 + ci] = 0;
        h1T[s*S1 + 21*64 + ci] = 0;
    }
    for (int idx = t; idx < SEGB*128; idx += 512) {
        int s = idx >> 7, co = idx & 127;
        hpT[s*S2 + co] = 0;
        hpT[s*S2 + 11*128 + co] = 0;
    }
    __syncthreads();

    // conv1
    {
        int ci = t & 63, sg = t >> 6;
        float ww0 = w1[ci*3], ww1 = w1[ci*3+1], ww2 = w1[ci*3+2], bb = b1[ci];
        #pragma unroll
        for (int si = 0; si < 2; ++si) {
            int s = sg*2 + si;
            #pragma unroll
            for (int l = 0; l < 20; ++l) {
                float v = xs[s][l]*ww0 + xs[s][l+1]*ww1 + xs[s][l+2]*ww2 + bb;
                h1T[s*S1 + (l+1)*64 + ci] = f2bf(gelu_f(v));
            }
        }
    }
    __syncthreads();

    // conv2 GEMM + gelu + maxpool
    {
        const int mh = wave & 3, ng = wave >> 2;
        f32x4 acc[2][10];
        #pragma unroll
        for (int mi = 0; mi < 2; ++mi)
            #pragma unroll
            for (int li = 0; li < 10; ++li) acc[mi][li] = (f32x4){0.f,0.f,0.f,0.f};

        for (int kt = 0; kt < 6; ++kt) {
            int k = kt >> 1, cih = (kt & 1) * 32;
            short8 a[2], b[10];
            #pragma unroll
            for (int mi = 0; mi < 2; ++mi)
                a[mi] = *(const short8*)(A2p + (((kt*8 + mh*2 + mi)*64 + lane) << 3));
            #pragma unroll
            for (int li = 0; li < 10; ++li) {
                int l = ng*10 + li;
                b[li] = *(short8*)&h1T[sL*S1 + (l + k)*64 + cih + gL*8];
            }
            #pragma unroll
            for (int mi = 0; mi < 2; ++mi)
                #pragma unroll
                for (int li = 0; li < 10; ++li)
                    acc[mi][li] = __builtin_amdgcn_mfma_f32_16x16x32_bf16(a[mi], b[li], acc[mi][li], 0, 0, 0);
        }
        #pragma unroll
        for (int mi = 0; mi < 2; ++mi) {
            int mt = mh*2 + mi;
            int co0 = mt*16 + gL*4;
            float4 bb = *(const float4*)(b2 + co0);
            float bbr[4] = {bb.x, bb.y, bb.z, bb.w};
            #pragma unroll
            for (int j = 0; j < 5; ++j) {
                int lp = ng*5 + j;
                unsigned short pk[4];
                #pragma unroll
                for (int r = 0; r < 4; ++r) {
                    float p0 = gelu_f(acc[mi][2*j][r]   + bbr[r]);
                    float p1 = gelu_f(acc[mi][2*j+1][r] + bbr[r]);
                    pk[r] = f2bf(fmaxf(p0, p1));
                }
                *(uint2*)&hpT[sL*S2 + (lp+1)*128 + co0] = *(uint2*)pk;
            }
        }
    }
    __syncthreads();

    // conv3 GEMM + gelu + mean
    {
        f32x4 acc[2][10];
        #pragma unroll
        for (int mi = 0; mi < 2; ++mi)
            #pragma unroll
            for (int li = 0; li < 10; ++li) acc[mi][li] = (f32x4){0.f,0.f,0.f,0.f};

        for (int kt = 0; kt < 12; ++kt) {
            int k = kt >> 2, ciq = (kt & 3) * 32;
            short8 a[2], b[10];
            #pragma unroll
            for (int mi = 0; mi < 2; ++mi)
                a[mi] = *(const short8*)(A3p + (((kt*16 + wave*2 + mi)*64 + lane) << 3));
            #pragma unroll
            for (int li = 0; li < 10; ++li)
                b[li] = *(short8*)&hpT[sL*S2 + (li + k)*128 + ciq + gL*8];
            #pragma unroll
            for (int mi = 0; mi < 2; ++mi)
                #pragma unroll
                for (int li = 0; li < 10; ++li)
                    acc[mi][li] = __builtin_amdgcn_mfma_f32_16x16x32_bf16(a[mi], b[li], acc[mi][li], 0, 0, 0);
        }
        int seg = seg0 + sL;
        int bI = seg / (C_*P_);
        int rem = seg % (C_*P_);
        int c = rem / P_, p = rem % P_;
        float* frow = feat + (((size_t)(bI*P_ + p)*C_ + c) << 8);
        #pragma unroll
        for (int mi = 0; mi < 2; ++mi) {
            int co0 = (wave*2 + mi)*16 + gL*4;
            float4 bv = *(const float4*)(b3 + co0);
            float bbr[4] = {bv.x, bv.y, bv.z, bv.w};
            float sum[4] = {0.f, 0.f, 0.f, 0.f};
            #pragma unroll
            for (int li = 0; li < 10; ++li)
                #pragma unroll
                for (int r = 0; r < 4; ++r)
                    sum[r] += gelu_f(acc[mi][li][r] + bbr[r]);
            float4 o;
            o.x = sum[0]*0.1f; o.y = sum[1]*0.1f; o.z = sum[2]*0.1f; o.w = sum[3]*0.1f;
            *(float4*)(frow + co0) = o;
        }
    }
}

// ---------------- kernel 2: fused mix + gelu + LN + proj (MFMA) ----------------
// One block per n2 = (b,p). LDS: fT[d:256][FT_STRIDE] bf16, then aliased mT[o:144][MT_STRIDE].
__global__ __launch_bounds__(512, 2) void mix_proj_kernel(
    const float* __restrict__ feat,
    const unsigned short* __restrict__ mixA, const float* __restrict__ bmixp,
    const float* __restrict__ lnwp, const float* __restrict__ lnbp,
    const unsigned short* __restrict__ projA, const float* __restrict__ proj_b,
    float* __restrict__ out)
{
    __shared__ __align__(16) unsigned short ulds[256*FT_STRIDE]; // 86016 B; mT (76032 B) aliases
    unsigned short* fT = ulds;
    unsigned short* mT = ulds;

    const int t = threadIdx.x;
    const int wave = t >> 6, lane = t & 63;
    const int sL = lane & 15, gL = lane >> 4;
    const int n2 = blockIdx.x;
    const int b = n2 / P_, p = n2 % P_;

    // ---- stage fT[d][c] = bf16(feat[n2][c][d]) ----
    const float* fbase = feat + (size_t)n2 * C_ * 256;
    for (int idx = t; idx < 129*256; idx += 512) {
        int c = idx >> 8, d = idx & 255;
        fT[d*FT_STRIDE + c] = f2bf(fbase[idx]);
    }
    for (int idx = t; idx < 256*31; idx += 512) {  // zero K-pad cols 129..159
        int d = idx / 31, c = 129 + idx % 31;
        fT[d*FT_STRIDE + c] = 0;
    }
    __syncthreads();

    // ---- mix GEMM: M=o(144), N=d(256), K=c(160). wave owns N-tiles {2w,2w+1} ----
    f32x4 acc[9][2];
    #pragma unroll
    for (int mt = 0; mt < 9; ++mt)
        #pragma unroll
        for (int nt = 0; nt < 2; ++nt) acc[mt][nt] = (f32x4){0.f,0.f,0.f,0.f};

    #pragma unroll
    for (int kt = 0; kt < 5; ++kt) {
        short8 bb[2];
        #pragma unroll
        for (int nt = 0; nt < 2; ++nt) {
            int d = (wave*2 + nt)*16 + sL;
            bb[nt] = *(const short8*)&fT[d*FT_STRIDE + kt*32 + gL*8];
        }
        #pragma unroll
        for (int mt = 0; mt < 9; ++mt) {
            short8 a = *(const short8*)(mixA + (((kt*9 + mt)*64 + lane) << 3));
            #pragma unroll
            for (int nt = 0; nt < 2; ++nt)
                acc[mt][nt] = __builtin_amdgcn_mfma_f32_16x16x32_bf16(a, bb[nt], acc[mt][nt], 0, 0, 0);
        }
    }

    // ---- epilogue: bias + gelu (mask o>=129), LN stats over o ----
    float sum[2] = {0.f, 0.f}, sq[2] = {0.f, 0.f};
    #pragma unroll
    for (int mt = 0; mt < 9; ++mt) {
        float4 bv = *(const float4*)(bmixp + mt*16 + gL*4);
        float bbr[4] = {bv.x, bv.y, bv.z, bv.w};
        #pragma unroll
        for (int nt = 0; nt < 2; ++nt) {
            #pragma unroll
            for (int r = 0; r < 4; ++r) {
                int o = mt*16 + gL*4 + r;
                float g = (o < 129) ? gelu_f(acc[mt][nt][r] + bbr[r]) : 0.f;
                acc[mt][nt][r] = g;
                sum[nt] += g;
                sq[nt]  += g*g;
            }
        }
    }
    float mu[2], rs[2];
    #pragma unroll
    for (int nt = 0; nt < 2; ++nt) {
        float s = sum[nt], q = sq[nt];
        s += __shfl_xor(s, 16); q += __shfl_xor(q, 16);
        s += __shfl_xor(s, 32); q += __shfl_xor(q, 32);
        mu[nt] = s * (1.f/129.f);
        float var = q * (1.f/129.f) - mu[nt]*mu[nt];
        rs[nt] = rsqrtf(var + 1e-5f);
    }

    __syncthreads();   // all fT reads done; safe to overwrite with mT

    // ---- apply LN, write mT[o][d] bf16 ----
    #pragma unroll
    for (int mt = 0; mt < 9; ++mt) {
        float4 lw = *(const float4*)(lnwp + mt*16 + gL*4);
        float4 lb = *(const float4*)(lnbp + mt*16 + gL*4);
        float lwr[4] = {lw.x, lw.y, lw.z, lw.w};
        float lbr[4] = {lb.x, lb.y, lb.z, lb.w};
        #pragma unroll
        for (int nt = 0; nt < 2; ++nt) {
            int d = (wave*2 + nt)*16 + sL;
            #pragma unroll
            for (int r = 0; r < 4; ++r) {
                int o = mt*16 + gL*4 + r;
                float y = (acc[mt][nt][r] - mu[nt]) * rs[nt] * lwr[r] + lbr[r];
                mT[o*MT_STRIDE + d] = f2bf(y);
            }
        }
    }
    __syncthreads();

    // ---- proj GEMM: M=e(256), N=o(144; store o<129), K=d(256). wave owns M-tiles {2w,2w+1} ----
    f32x4 pacc[2][9];
    #pragma unroll
    for (int mi = 0; mi < 2; ++mi)
        #pragma unroll
        for (int nt = 0; nt < 9; ++nt) pacc[mi][nt] = (f32x4){0.f,0.f,0.f,0.f};

    #pragma unroll
    for (int kt = 0; kt < 8; ++kt) {
        short8 a[2];
        #pragma unroll
        for (int mi = 0; mi < 2; ++mi)
            a[mi] = *(const short8*)(projA + (((kt*16 + wave*2 + mi)*64 + lane) << 3));
        #pragma unroll
        for (int nt = 0; nt < 9; ++nt) {
            short8 bb = *(const short8*)&mT[(nt*16 + sL)*MT_STRIDE + kt*32 + gL*8];
            #pragma unroll
            for (int mi = 0; mi < 2; ++mi)
                pacc[mi][nt] = __builtin_amdgcn_mfma_f32_16x16x32_bf16(a[mi], bb, pacc[mi][nt], 0, 0, 0);
        }
    }

    // ---- output: out[b][c][p][e] ----
    #pragma unroll
    for (int mi = 0; mi < 2; ++mi) {
        int e0 = (wave*2 + mi)*16 + gL*4;
        float4 pb4 = *(const float4*)(proj_b + e0);
        #pragma unroll
        for (int nt = 0; nt < 9; ++nt) {
            int c = nt*16 + sL;
            if (c < 129) {
                float4 o4;
                o4.x = pacc[mi][nt][0] + pb4.x;
                o4.y = pacc[mi][nt][1] + pb4.y;
                o4.z = pacc[mi][nt][2] + pb4.z;
                o4.w = pacc[mi][nt][3] + pb4.w;
                *(float4*)&out[(((size_t)(b*C_ + c)*P_) + p)*256 + e0] = o4;
            }
        }
    }
}

extern "C" void kernel_launch(void* const* d_in, const int* in_sizes, int n_in,
                              void* d_out, int out_size, void* d_ws, size_t ws_size,
                              hipStream_t stream) {
    (void)in_sizes; (void)n_in; (void)out_size; (void)ws_size;
    const float* x    = (const float*)d_in[0];
    const float* w1   = (const float*)d_in[1];
    const float* b1   = (const float*)d_in[2];
    const float* w2   = (const float*)d_in[3];
    const float* b2   = (const float*)d_in[4];
    const float* w3   = (const float*)d_in[5];
    const float* b3   = (const float*)d_in[6];
    const float* mixw = (const float*)d_in[7];
    const float* mixb = (const float*)d_in[8];
    const float* lnw  = (const float*)d_in[9];
    const float* lnb  = (const float*)d_in[10];
    const float* pw   = (const float*)d_in[11];
    const float* pb   = (const float*)d_in[12];
    float* out = (float*)d_out;
    float* ws  = (float*)d_ws;

    // workspace layout
    float* feat = ws;                                        // 63984*256 floats
    unsigned short* A2p  = (unsigned short*)(ws + 16379904); // 24576 u16
    unsigned short* A3p  = A2p + 24576;                      // 98304 u16
    unsigned short* mixA = A3p + 98304;                      // 23040 u16
    unsigned short* projA = mixA + 23040;                    // 65536 u16
    float* bmixp = (float*)(projA + 65536);                  // 144
    float* lnwp  = bmixp + 144;                              // 144
    float* lnbp  = lnwp + 144;                               // 144

    prep_kernel<<<256, 256, 0, stream>>>(w2, w3, mixw, pw, mixb, lnw, lnb,
                                         A2p, A3p, mixA, projA, bmixp, lnwp, lnbp);
    conv_mfma_kernel<<<NWG, 512, 0, stream>>>(x, w1, b1, A2p, b2, A3p, b3, feat);
    mix_proj_kernel<<<N2, 512, 0, stream>>>(feat, mixA, bmixp, lnwp, lnbp, projA, pb, out);
}

// Round 5
// 390.875 us; speedup vs baseline: 10.8844x; 1.6949x over previous
//
#include <hip/hip_runtime.h>

#define B_ 8
#define C_ 129
#define P_ 62
#define L_ 20
#define D_ 256
#define NSEG (B_*C_*P_)   /* 63984 */
#define N2   (B_*P_)      /* 496 */
#define SEGB 16
#define NWG  (NSEG/SEGB)  /* 3999 */

#define S1 1416   /* h1T per-seg stride in u16 */
#define S2 1544   /* hpT per-seg stride in u16 */

#define FT_STRIDE 168   /* fT [256 d][168] u16 */
#define MT_STRIDE 264   /* mT [144 o][264] u16 */

typedef short short8 __attribute__((ext_vector_type(8)));
typedef float f32x4  __attribute__((ext_vector_type(4)));

// Branchless erf-GELU via Abramowitz-Stegun 7.1.26 (max |erf err| 1.5e-7).
// gelu(x) = 0.5*x*(1+erf(x/sqrt2)); erf(|u|) = 1 - poly(t)*exp(-u^2), t=1/(1+p|u|)
__device__ __forceinline__ float gelu_f(float x) {
    float u  = 0.70710678f * x;
    float au = __builtin_fabsf(u);
    float t  = __builtin_amdgcn_rcpf(fmaf(0.3275911f, au, 1.0f));
    float p  = fmaf(1.061405429f, t, -1.453152027f);
    p = fmaf(p, t, 1.421413741f);
    p = fmaf(p, t, -0.284496736f);
    p = fmaf(p, t, 0.254829592f);
    p = p * t;
    float e  = __builtin_amdgcn_exp2f(-1.4426950409f * au * au);
    float ea = fmaf(-p, e, 1.0f);          // erf(|u|) in [0,1)
    float er = copysignf(ea, u);           // erf(u)
    return 0.5f * x * (1.0f + er);
}
__device__ __forceinline__ unsigned short f2bf(float f) {
    unsigned u = __float_as_uint(f);
    u = u + 0x7FFFu + ((u >> 16) & 1u);
    return (unsigned short)(u >> 16);
}

// ---------------- prep: pack all weights into MFMA fragment order ----------------
__global__ void prep_kernel(const float* __restrict__ w2, const float* __restrict__ w3,
                            const float* __restrict__ mw, const float* __restrict__ pw,
                            const float* __restrict__ mixb, const float* __restrict__ lnw,
                            const float* __restrict__ lnb,
                            unsigned short* __restrict__ A2p, unsigned short* __restrict__ A3p,
                            unsigned short* __restrict__ mixA, unsigned short* __restrict__ projA,
                            float* __restrict__ bmixp, float* __restrict__ lnwp,
                            float* __restrict__ lnbp) {
    int idx = blockIdx.x * blockDim.x + threadIdx.x;
    int stride = gridDim.x * blockDim.x;
    for (int f = idx; f < 6*8*64*8; f += stride) {
        int j = f & 7, ln = (f >> 3) & 63, mt = (f >> 9) & 7, kt = f >> 12;
        int co = mt*16 + (ln & 15);
        int k  = kt >> 1;
        int ci = (kt & 1)*32 + (ln >> 4)*8 + j;
        A2p[f] = f2bf(w2[(co*64 + ci)*3 + k]);
    }
    for (int f = idx; f < 12*16*64*8; f += stride) {
        int j = f & 7, ln = (f >> 3) & 63, mt = (f >> 9) & 15, kt = f >> 13;
        int co = mt*16 + (ln & 15);
        int k  = kt >> 2;
        int ci = (kt & 3)*32 + (ln >> 4)*8 + j;
        A3p[f] = f2bf(w3[(co*128 + ci)*3 + k]);
    }
    for (int f = idx; f < 5*9*64*8; f += stride) {
        int j = f & 7, ln = (f >> 3) & 63;
        int mt = (f >> 9) % 9, kt = (f >> 9) / 9;
        int o = mt*16 + (ln & 15);
        int c = kt*32 + (ln >> 4)*8 + j;
        mixA[f] = (o < 129 && c < 129) ? f2bf(mw[o*129 + c]) : (unsigned short)0;
    }
    for (int f = idx; f < 8*16*64*8; f += stride) {
        int j = f & 7, ln = (f >> 3) & 63, mt = (f >> 9) & 15, kt = f >> 13;
        int e = mt*16 + (ln & 15);
        int d = kt*32 + (ln >> 4)*8 + j;
        projA[f] = f2bf(pw[e*256 + d]);
    }
    for (int i = idx; i < 144; i += stride) {
        bmixp[i] = (i < 129) ? mixb[i] : 0.f;
        lnwp[i]  = (i < 129) ? lnw[i]  : 0.f;
        lnbp[i]  = (i < 129) ? lnb[i]  : 0.f;
    }
}

// ---------------- kernel 1: conv stack via MFMA ----------------
__global__ __launch_bounds__(512, 2) void conv_mfma_kernel(
    const float* __restrict__ x,
    const float* __restrict__ w1, const float* __restrict__ b1,
    const unsigned short* __restrict__ A2p, const float* __restrict__ b2,
    const unsigned short* __restrict__ A3p, const float* __restrict__ b3,
    float* __restrict__ feat)
{
    __shared__ __align__(16) unsigned short h1T[SEGB * S1];
    __shared__ __align__(16) unsigned short hpT[SEGB * S2];
    __shared__ float xs[SEGB][22];

    const int t = threadIdx.x;
    const int wave = t >> 6, lane = t & 63;
    const int sL = lane & 15, gL = lane >> 4;
    const int seg0 = blockIdx.x * SEGB;

    for (int idx = t; idx < SEGB*22; idx += 512) {
        int s = idx / 22, i = idx % 22;
        float v = 0.f;
        if (i >= 1 && i <= 20) v = x[(seg0 + s)*L_ + i - 1];
        xs[s][i] = v;
    }
    for (int idx = t; idx < SEGB*64; idx += 512) {
        int s = idx >> 6, ci = idx & 63;
        h1T[s*S1 + ci] = 0;
        h1T[s*S1 + 21*64 + ci] = 0;
    }
    for (int idx = t; idx < SEGB*128; idx += 512) {
        int s = idx >> 7, co = idx & 127;
        hpT[s*S2 + co] = 0;
        hpT[s*S2 + 11*128 + co] = 0;
    }
    __syncthreads();

    // conv1: 1 -> 64, paired channels, b32 LDS writes
    {
        int seg = t >> 5, cp = t & 31;
        int ci0 = cp * 2;
        float wa0 = w1[ci0*3+0], wa1 = w1[ci0*3+1], wa2 = w1[ci0*3+2], ba = b1[ci0];
        float wb0 = w1[ci0*3+3], wb1 = w1[ci0*3+4], wb2 = w1[ci0*3+5], bb = b1[ci0+1];
        unsigned short* dst = &h1T[seg*S1 + ci0];
        #pragma unroll
        for (int l = 0; l < 20; ++l) {
            float x0 = xs[seg][l], x1 = xs[seg][l+1], x2v = xs[seg][l+2];
            float va = fmaf(x0, wa0, fmaf(x1, wa1, fmaf(x2v, wa2, ba)));
            float vb = fmaf(x0, wb0, fmaf(x1, wb1, fmaf(x2v, wb2, bb)));
            unsigned pk = (unsigned)f2bf(gelu_f(va)) | ((unsigned)f2bf(gelu_f(vb)) << 16);
            *(unsigned*)(dst + (l+1)*64) = pk;
        }
    }
    __syncthreads();

    // conv2 GEMM: M=128, N=320, K=192; register-cached B rows; gelu THEN maxpool (exact)
    {
        const int mh = wave & 3, ng = wave >> 2;
        f32x4 acc[2][10];
        #pragma unroll
        for (int mi = 0; mi < 2; ++mi)
            #pragma unroll
            for (int li = 0; li < 10; ++li) acc[mi][li] = (f32x4){0.f,0.f,0.f,0.f};

        const unsigned short* h1base = &h1T[sL*S1 + ng*640 + gL*8];
        #pragma unroll
        for (int h = 0; h < 2; ++h) {
            short8 br[12];
            #pragma unroll
            for (int r = 0; r < 12; ++r)
                br[r] = *(const short8*)(h1base + r*64 + h*32);
            #pragma unroll
            for (int k = 0; k < 3; ++k) {
                int kt = k*2 + h;
                short8 a0 = *(const short8*)(A2p + (((kt*8 + mh*2 + 0)*64 + lane) << 3));
                short8 a1 = *(const short8*)(A2p + (((kt*8 + mh*2 + 1)*64 + lane) << 3));
                #pragma unroll
                for (int li = 0; li < 10; ++li) {
                    acc[0][li] = __builtin_amdgcn_mfma_f32_16x16x32_bf16(a0, br[li+k], acc[0][li], 0, 0, 0);
                    acc[1][li] = __builtin_amdgcn_mfma_f32_16x16x32_bf16(a1, br[li+k], acc[1][li], 0, 0, 0);
                }
            }
        }
        // epilogue: +bias, gelu both, then max (reference order)
        #pragma unroll
        for (int mi = 0; mi < 2; ++mi) {
            int mt = mh*2 + mi;
            int co0 = mt*16 + gL*4;
            float4 bb = *(const float4*)(b2 + co0);
            float bbr[4] = {bb.x, bb.y, bb.z, bb.w};
            #pragma unroll
            for (int j = 0; j < 5; ++j) {
                int lp = ng*5 + j;
                unsigned short pk[4];
                #pragma unroll
                for (int r = 0; r < 4; ++r) {
                    float p0 = gelu_f(acc[mi][2*j][r]   + bbr[r]);
                    float p1 = gelu_f(acc[mi][2*j+1][r] + bbr[r]);
                    pk[r] = f2bf(fmaxf(p0, p1));
                }
                *(uint2*)&hpT[sL*S2 + (lp+1)*128 + co0] = *(uint2*)pk;
            }
        }
    }
    __syncthreads();

    // conv3 GEMM: M=256, N=160, K=384; register-cached B rows; gelu + mean
    {
        f32x4 acc[2][10];
        #pragma unroll
        for (int mi = 0; mi < 2; ++mi)
            #pragma unroll
            for (int li = 0; li < 10; ++li) acc[mi][li] = (f32x4){0.f,0.f,0.f,0.f};

        const unsigned short* hpbase = &hpT[sL*S2 + gL*8];
        #pragma unroll
        for (int q = 0; q < 4; ++q) {
            short8 br[12];
            #pragma unroll
            for (int r = 0; r < 12; ++r)
                br[r] = *(const short8*)(hpbase + r*128 + q*32);
            #pragma unroll
            for (int k = 0; k < 3; ++k) {
                int kt = k*4 + q;
                short8 a0 = *(const short8*)(A3p + (((kt*16 + wave*2 + 0)*64 + lane) << 3));
                short8 a1 = *(const short8*)(A3p + (((kt*16 + wave*2 + 1)*64 + lane) << 3));
                #pragma unroll
                for (int li = 0; li < 10; ++li) {
                    acc[0][li] = __builtin_amdgcn_mfma_f32_16x16x32_bf16(a0, br[li+k], acc[0][li], 0, 0, 0);
                    acc[1][li] = __builtin_amdgcn_mfma_f32_16x16x32_bf16(a1, br[li+k], acc[1][li], 0, 0, 0);
                }
            }
        }
        int seg = seg0 + sL;
        int bI = seg / (C_*P_);
        int rem = seg % (C_*P_);
        int c = rem / P_, p = rem % P_;
        float* frow = feat + (((size_t)(bI*P_ + p)*C_ + c) << 8);
        #pragma unroll
        for (int mi = 0; mi < 2; ++mi) {
            int co0 = (wave*2 + mi)*16 + gL*4;
            float4 bv = *(const float4*)(b3 + co0);
            float bbr[4] = {bv.x, bv.y, bv.z, bv.w};
            float sum[4] = {0.f, 0.f, 0.f, 0.f};
            #pragma unroll
            for (int li = 0; li < 10; ++li)
                #pragma unroll
                for (int r = 0; r < 4; ++r)
                    sum[r] += gelu_f(acc[mi][li][r] + bbr[r]);
            float4 o;
            o.x = sum[0]*0.1f; o.y = sum[1]*0.1f; o.z = sum[2]*0.1f; o.w = sum[3]*0.1f;
            *(float4*)(frow + co0) = o;
        }
    }
}

// ---------------- kernel 2: fused mix + gelu + LN + proj (MFMA) ----------------
__global__ __launch_bounds__(512, 2) void mix_proj_kernel(
    const float* __restrict__ feat,
    const unsigned short* __restrict__ mixA, const float* __restrict__ bmixp,
    const float* __restrict__ lnwp, const float* __restrict__ lnbp,
    const unsigned short* __restrict__ projA, const float* __restrict__ proj_b,
    float* __restrict__ out)
{
    __shared__ __align__(16) unsigned short ulds[256*FT_STRIDE];
    unsigned short* fT = ulds;
    unsigned short* mT = ulds;

    const int t = threadIdx.x;
    const int wave = t >> 6, lane = t & 63;
    const int sL = lane & 15, gL = lane >> 4;
    const int n2 = blockIdx.x;
    const int b = n2 / P_, p = n2 % P_;

    const float* fbase = feat + (size_t)n2 * C_ * 256;
    for (int idx = t; idx < 129*256; idx += 512) {
        int c = idx >> 8, d = idx & 255;
        fT[d*FT_STRIDE + c] = f2bf(fbase[idx]);
    }
    for (int idx = t; idx < 256*31; idx += 512) {
        int d = idx / 31, c = 129 + idx % 31;
        fT[d*FT_STRIDE + c] = 0;
    }
    __syncthreads();

    f32x4 acc[9][2];
    #pragma unroll
    for (int mt = 0; mt < 9; ++mt)
        #pragma unroll
        for (int nt = 0; nt < 2; ++nt) acc[mt][nt] = (f32x4){0.f,0.f,0.f,0.f};

    #pragma unroll
    for (int kt = 0; kt < 5; ++kt) {
        short8 bb[2];
        #pragma unroll
        for (int nt = 0; nt < 2; ++nt) {
            int d = (wave*2 + nt)*16 + sL;
            bb[nt] = *(const short8*)&fT[d*FT_STRIDE + kt*32 + gL*8];
        }
        #pragma unroll
        for (int mt = 0; mt < 9; ++mt) {
            short8 a = *(const short8*)(mixA + (((kt*9 + mt)*64 + lane) << 3));
            #pragma unroll
            for (int nt = 0; nt < 2; ++nt)
                acc[mt][nt] = __builtin_amdgcn_mfma_f32_16x16x32_bf16(a, bb[nt], acc[mt][nt], 0, 0, 0);
        }
    }

    float sum[2] = {0.f, 0.f}, sq[2] = {0.f, 0.f};
    #pragma unroll
    for (int mt = 0; mt < 9; ++mt) {
        float4 bv = *(const float4*)(bmixp + mt*16 + gL*4);
        float bbr[4] = {bv.x, bv.y, bv.z, bv.w};
        #pragma unroll
        for (int nt = 0; nt < 2; ++nt) {
            #pragma unroll
            for (int r = 0; r < 4; ++r) {
                int o = mt*16 + gL*4 + r;
                float g = (o < 129) ? gelu_f(acc[mt][nt][r] + bbr[r]) : 0.f;
                acc[mt][nt][r] = g;
                sum[nt] += g;
                sq[nt]  += g*g;
            }
        }
    }
    float mu[2], rs[2];
    #pragma unroll
    for (int nt = 0; nt < 2; ++nt) {
        float s = sum[nt], q = sq[nt];
        s += __shfl_xor(s, 16); q += __shfl_xor(q, 16);
        s += __shfl_xor(s, 32); q += __shfl_xor(q, 32);
        mu[nt] = s * (1.f/129.f);
        float var = q * (1.f/129.f) - mu[nt]*mu[nt];
        rs[nt] = rsqrtf(var + 1e-5f);
    }

    __syncthreads();

    #pragma unroll
    for (int mt = 0; mt < 9; ++mt) {
        float4 lw = *(const float4*)(lnwp + mt*16 + gL*4);
        float4 lb = *(const float4*)(lnbp + mt*16 + gL*4);
        float lwr[4] = {lw.x, lw.y, lw.z, lw.w};
        float lbr[4] = {lb.x, lb.y, lb.z, lb.w};
        #pragma unroll
        for (int nt = 0; nt < 2; ++nt) {
            int d = (wave*2 + nt)*16 + sL;
            #pragma unroll
            for (int r = 0; r < 4; ++r) {
                int o = mt*16 + gL*4 + r;
                float y = (acc[mt][nt][r] - mu[nt]) * rs[nt] * lwr[r] + lbr[r];
                mT[o*MT_STRIDE + d] = f2bf(y);
            }
        }
    }
    __syncthreads();

    f32x4 pacc[2][9];
    #pragma unroll
    for (int mi = 0; mi < 2; ++mi)
        #pragma unroll
        for (int nt = 0; nt < 9; ++nt) pacc[mi][nt] = (f32x4){0.f,0.f,0.f,0.f};

    #pragma unroll
    for (int kt = 0; kt < 8; ++kt) {
        short8 a[2];
        #pragma unroll
        for (int mi = 0; mi < 2; ++mi)
            a[mi] = *(const short8*)(projA + (((kt*16 + wave*2 + mi)*64 + lane) << 3));
        #pragma unroll
        for (int nt = 0; nt < 9; ++nt) {
            short8 bb = *(const short8*)&mT[(nt*16 + sL)*MT_STRIDE + kt*32 + gL*8];
            #pragma unroll
            for (int mi = 0; mi < 2; ++mi)
                pacc[mi][nt] = __builtin_amdgcn_mfma_f32_16x16x32_bf16(a[mi], bb, pacc[mi][nt], 0, 0, 0);
        }
    }

    #pragma unroll
    for (int mi = 0; mi < 2; ++mi) {
        int e0 = (wave*2 + mi)*16 + gL*4;
        float4 pb4 = *(const float4*)(proj_b + e0);
        #pragma unroll
        for (int nt = 0; nt < 9; ++nt) {
            int c = nt*16 + sL;
            if (c < 129) {
                float4 o4;
                o4.x = pacc[mi][nt][0] + pb4.x;
                o4.y = pacc[mi][nt][1] + pb4.y;
                o4.z = pacc[mi][nt][2] + pb4.z;
                o4.w = pacc[mi][nt][3] + pb4.w;
                *(float4*)&out[(((size_t)(b*C_ + c)*P_) + p)*256 + e0] = o4;
            }
        }
    }
}

extern "C" void kernel_launch(void* const* d_in, const int* in_sizes, int n_in,
                              void* d_out, int out_size, void* d_ws, size_t ws_size,
                              hipStream_t stream) {
    (void)in_sizes; (void)n_in; (void)out_size; (void)ws_size;
    const float* x    = (const float*)d_in[0];
    const float* w1   = (const float*)d_in[1];
    const float* b1   = (const float*)d_in[2];
    const float* w2   = (const float*)d_in[3];
    const float* b2   = (const float*)d_in[4];
    const float* w3   = (const float*)d_in[5];
    const float* b3   = (const float*)d_in[6];
    const float* mixw = (const float*)d_in[7];
    const float* mixb = (const float*)d_in[8];
    const float* lnw  = (const float*)d_in[9];
    const float* lnb  = (const float*)d_in[10];
    const float* pw   = (const float*)d_in[11];
    const float* pb   = (const float*)d_in[12];
    float* out = (float*)d_out;
    float* ws  = (float*)d_ws;

    float* feat = ws;                                        // 63984*256 floats
    unsigned short* A2p  = (unsigned short*)(ws + 16379904); // 24576 u16
    unsigned short* A3p  = A2p + 24576;                      // 98304 u16
    unsigned short* mixA = A3p + 98304;                      // 23040 u16
    unsigned short* projA = mixA + 23040;                    // 65536 u16
    float* bmixp = (float*)(projA + 65536);                  // 144
    float* lnwp  = bmixp + 144;                              // 144
    float* lnbp  = lnwp + 144;                               // 144

    prep_kernel<<<256, 256, 0, stream>>>(w2, w3, mixw, pw, mixb, lnw, lnb,
                                         A2p, A3p, mixA, projA, bmixp, lnwp, lnbp);
    conv_mfma_kernel<<<NWG, 512, 0, stream>>>(x, w1, b1, A2p, b2, A3p, b3, feat);
    mix_proj_kernel<<<N2, 512, 0, stream>>>(feat, mixA, bmixp, lnwp, lnbp, projA, pb, out);
}

// Round 6
// 388.549 us; speedup vs baseline: 10.9495x; 1.0060x over previous
//
#include <hip/hip_runtime.h>

#define B_ 8
#define C_ 129
#define P_ 62
#define L_ 20
#define D_ 256
#define NSEG (B_*C_*P_)   /* 63984 */
#define N2   (B_*P_)      /* 496 */
#define SEGB 8
#define NWG  (NSEG/SEGB)  /* 7998 */

#define S1 1416   /* h1T per-seg stride in u16 */
#define S2 1544   /* hpT per-seg stride in u16 */

#define FT_STRIDE 168   /* fT [256 d][168] u16 */
#define MT_STRIDE 264   /* mT [144 o][264] u16 */

typedef short short8 __attribute__((ext_vector_type(8)));
typedef float f32x4  __attribute__((ext_vector_type(4)));

// Branchless erf-GELU via Abramowitz-Stegun 7.1.26 (max |erf err| 1.5e-7).
__device__ __forceinline__ float gelu_f(float x) {
    float u  = 0.70710678f * x;
    float au = __builtin_fabsf(u);
    float t  = __builtin_amdgcn_rcpf(fmaf(0.3275911f, au, 1.0f));
    float p  = fmaf(1.061405429f, t, -1.453152027f);
    p = fmaf(p, t, 1.421413741f);
    p = fmaf(p, t, -0.284496736f);
    p = fmaf(p, t, 0.254829592f);
    p = p * t;
    float e  = __builtin_amdgcn_exp2f(-1.4426950409f * au * au);
    float ea = fmaf(-p, e, 1.0f);
    float er = copysignf(ea, u);
    return 0.5f * x * (1.0f + er);
}
__device__ __forceinline__ unsigned short f2bf(float f) {
    unsigned u = __float_as_uint(f);
    u = u + 0x7FFFu + ((u >> 16) & 1u);
    return (unsigned short)(u >> 16);
}

// ---------------- prep: pack all weights into MFMA fragment order ----------------
__global__ void prep_kernel(const float* __restrict__ w2, const float* __restrict__ w3,
                            const float* __restrict__ mw, const float* __restrict__ pw,
                            const float* __restrict__ mixb, const float* __restrict__ lnw,
                            const float* __restrict__ lnb,
                            unsigned short* __restrict__ A2p, unsigned short* __restrict__ A3p,
                            unsigned short* __restrict__ mixA, unsigned short* __restrict__ projA,
                            float* __restrict__ bmixp, float* __restrict__ lnwp,
                            float* __restrict__ lnbp) {
    int idx = blockIdx.x * blockDim.x + threadIdx.x;
    int stride = gridDim.x * blockDim.x;
    for (int f = idx; f < 6*8*64*8; f += stride) {
        int j = f & 7, ln = (f >> 3) & 63, mt = (f >> 9) & 7, kt = f >> 12;
        int co = mt*16 + (ln & 15);
        int k  = kt >> 1;
        int ci = (kt & 1)*32 + (ln >> 4)*8 + j;
        A2p[f] = f2bf(w2[(co*64 + ci)*3 + k]);
    }
    for (int f = idx; f < 12*16*64*8; f += stride) {
        int j = f & 7, ln = (f >> 3) & 63, mt = (f >> 9) & 15, kt = f >> 13;
        int co = mt*16 + (ln & 15);
        int k  = kt >> 2;
        int ci = (kt & 3)*32 + (ln >> 4)*8 + j;
        A3p[f] = f2bf(w3[(co*128 + ci)*3 + k]);
    }
    for (int f = idx; f < 5*9*64*8; f += stride) {
        int j = f & 7, ln = (f >> 3) & 63;
        int mt = (f >> 9) % 9, kt = (f >> 9) / 9;
        int o = mt*16 + (ln & 15);
        int c = kt*32 + (ln >> 4)*8 + j;
        mixA[f] = (o < 129 && c < 129) ? f2bf(mw[o*129 + c]) : (unsigned short)0;
    }
    for (int f = idx; f < 8*16*64*8; f += stride) {
        int j = f & 7, ln = (f >> 3) & 63, mt = (f >> 9) & 15, kt = f >> 13;
        int e = mt*16 + (ln & 15);
        int d = kt*32 + (ln >> 4)*8 + j;
        projA[f] = f2bf(pw[e*256 + d]);
    }
    for (int i = idx; i < 144; i += stride) {
        bmixp[i] = (i < 129) ? mixb[i] : 0.f;
        lnwp[i]  = (i < 129) ? lnw[i]  : 0.f;
        lnbp[i]  = (i < 129) ? lnb[i]  : 0.f;
    }
}

// ---------------- kernel 1: conv stack via MFMA, SEGB=8 (2 blocks/CU) ----------------
// N interleave: n = pos*8 + seg. One 16-wide N-tile = positions {2t,2t+1} x 8 segs.
// Pool pair / mean parity combine via __shfl_xor(.,8) (lanes L and L^8 share gL, co).
__global__ __launch_bounds__(512, 4) void conv_mfma_kernel(
    const float* __restrict__ x,
    const float* __restrict__ w1, const float* __restrict__ b1,
    const unsigned short* __restrict__ A2p, const float* __restrict__ b2,
    const unsigned short* __restrict__ A3p, const float* __restrict__ b3,
    float* __restrict__ feat)
{
    __shared__ __align__(16) unsigned short h1T[SEGB * S1]; // 22656 B
    __shared__ __align__(16) unsigned short hpT[SEGB * S2]; // 24704 B
    __shared__ float xs[SEGB][22];                          //   704 B

    const int t = threadIdx.x;
    const int wave = t >> 6, lane = t & 63;
    const int sL = lane & 15, gL = lane >> 4;
    const int seg8 = sL & 7, hi8 = sL >> 3;
    const int seg0 = blockIdx.x * SEGB;

    for (int idx = t; idx < SEGB*22; idx += 512) {
        int s = idx / 22, i = idx % 22;
        float v = 0.f;
        if (i >= 1 && i <= 20) v = x[(seg0 + s)*L_ + i - 1];
        xs[s][i] = v;
    }
    for (int idx = t; idx < SEGB*64; idx += 512) {
        int s = idx >> 6, ci = idx & 63;
        h1T[s*S1 + ci] = 0;
        h1T[s*S1 + 21*64 + ci] = 0;
    }
    for (int idx = t; idx < SEGB*128; idx += 512) {
        int s = idx >> 7, co = idx & 127;
        hpT[s*S2 + co] = 0;
        hpT[s*S2 + 11*128 + co] = 0;
    }
    __syncthreads();

    // conv1: wave w owns seg w; lane = (chpair:5b, poshalf:1b); b32 packed writes
    {
        int seg = wave;
        int cp = (lane >> 1) & 31, ph = lane & 1;
        int ci0 = cp * 2;
        float wa0 = w1[ci0*3+0], wa1 = w1[ci0*3+1], wa2 = w1[ci0*3+2], ba = b1[ci0];
        float wb0 = w1[ci0*3+3], wb1 = w1[ci0*3+4], wb2 = w1[ci0*3+5], bb = b1[ci0+1];
        unsigned short* dst = &h1T[seg*S1 + ci0];
        #pragma unroll
        for (int i = 0; i < 10; ++i) {
            int l = ph*10 + i;
            float x0 = xs[seg][l], x1 = xs[seg][l+1], x2v = xs[seg][l+2];
            float va = fmaf(x0, wa0, fmaf(x1, wa1, fmaf(x2v, wa2, ba)));
            float vb = fmaf(x0, wb0, fmaf(x1, wb1, fmaf(x2v, wb2, bb)));
            unsigned pk = (unsigned)f2bf(gelu_f(va)) | ((unsigned)f2bf(gelu_f(vb)) << 16);
            *(unsigned*)(dst + (l+1)*64) = pk;
        }
    }
    __syncthreads();

    // conv2 GEMM: M=128, N=160, K=192. Wave: 2 M-tiles (mh), 5 N-tiles (ng half).
    // Per-lane pos = ng*10 + 2*nt + hi8; cached rows ng*10 + hi8 + r.
    {
        const int mh = wave & 3, ng = wave >> 2;
        f32x4 acc[2][5];
        #pragma unroll
        for (int mi = 0; mi < 2; ++mi)
            #pragma unroll
            for (int n = 0; n < 5; ++n) acc[mi][n] = (f32x4){0.f,0.f,0.f,0.f};

        const unsigned short* h1base = &h1T[seg8*S1 + (ng*10 + hi8)*64 + gL*8];
        #pragma unroll
        for (int h = 0; h < 2; ++h) {
            short8 br[11];
            #pragma unroll
            for (int r = 0; r < 11; ++r)
                br[r] = *(const short8*)(h1base + r*64 + h*32);
            #pragma unroll
            for (int k = 0; k < 3; ++k) {
                int kt = k*2 + h;
                short8 a0 = *(const short8*)(A2p + (((kt*8 + mh*2 + 0)*64 + lane) << 3));
                short8 a1 = *(const short8*)(A2p + (((kt*8 + mh*2 + 1)*64 + lane) << 3));
                #pragma unroll
                for (int n = 0; n < 5; ++n) {
                    acc[0][n] = __builtin_amdgcn_mfma_f32_16x16x32_bf16(a0, br[2*n+k], acc[0][n], 0, 0, 0);
                    acc[1][n] = __builtin_amdgcn_mfma_f32_16x16x32_bf16(a1, br[2*n+k], acc[1][n], 0, 0, 0);
                }
            }
        }
        // epilogue: +bias, gelu both parities, cross-lane max, lanes hi8==0 store
        #pragma unroll
        for (int mi = 0; mi < 2; ++mi) {
            int mt = mh*2 + mi;
            int co0 = mt*16 + gL*4;
            float4 bb = *(const float4*)(b2 + co0);
            float bbr[4] = {bb.x, bb.y, bb.z, bb.w};
            #pragma unroll
            for (int n = 0; n < 5; ++n) {
                int lp = ng*5 + n;
                float pv[4];
                #pragma unroll
                for (int r = 0; r < 4; ++r) {
                    float g = gelu_f(acc[mi][n][r] + bbr[r]);
                    pv[r] = fmaxf(g, __shfl_xor(g, 8));
                }
                if (hi8 == 0) {
                    unsigned short pk[4];
                    #pragma unroll
                    for (int r = 0; r < 4; ++r) pk[r] = f2bf(pv[r]);
                    *(uint2*)&hpT[seg8*S2 + (lp+1)*128 + co0] = *(uint2*)pk;
                }
            }
        }
    }
    __syncthreads();

    // conv3 GEMM: M=256, N=80, K=384. Wave: 2 M-tiles, all 5 N-tiles.
    // Per-lane pos = 2*nt + hi8; cached rows hi8 + r. Mean: in-lane + shfl_xor(8).
    {
        f32x4 acc[2][5];
        #pragma unroll
        for (int mi = 0; mi < 2; ++mi)
            #pragma unroll
            for (int n = 0; n < 5; ++n) acc[mi][n] = (f32x4){0.f,0.f,0.f,0.f};

        const unsigned short* hpbase = &hpT[seg8*S2 + hi8*128 + gL*8];
        #pragma unroll
        for (int q = 0; q < 4; ++q) {
            short8 br[11];
            #pragma unroll
            for (int r = 0; r < 11; ++r)
                br[r] = *(const short8*)(hpbase + r*128 + q*32);
            #pragma unroll
            for (int k = 0; k < 3; ++k) {
                int kt = k*4 + q;
                short8 a0 = *(const short8*)(A3p + (((kt*16 + wave*2 + 0)*64 + lane) << 3));
                short8 a1 = *(const short8*)(A3p + (((kt*16 + wave*2 + 1)*64 + lane) << 3));
                #pragma unroll
                for (int n = 0; n < 5; ++n) {
                    acc[0][n] = __builtin_amdgcn_mfma_f32_16x16x32_bf16(a0, br[2*n+k], acc[0][n], 0, 0, 0);
                    acc[1][n] = __builtin_amdgcn_mfma_f32_16x16x32_bf16(a1, br[2*n+k], acc[1][n], 0, 0, 0);
                }
            }
        }
        int seg = seg0 + seg8;
        int bI = seg / (C_*P_);
        int rem = seg % (C_*P_);
        int c = rem / P_, p = rem % P_;
        float* frow = feat + (((size_t)(bI*P_ + p)*C_ + c) << 8);
        #pragma unroll
        for (int mi = 0; mi < 2; ++mi) {
            int co0 = (wave*2 + mi)*16 + gL*4;
            float4 bv = *(const float4*)(b3 + co0);
            float bbr[4] = {bv.x, bv.y, bv.z, bv.w};
            float sum[4] = {0.f, 0.f, 0.f, 0.f};
            #pragma unroll
            for (int n = 0; n < 5; ++n)
                #pragma unroll
                for (int r = 0; r < 4; ++r)
                    sum[r] += gelu_f(acc[mi][n][r] + bbr[r]);
            #pragma unroll
            for (int r = 0; r < 4; ++r)
                sum[r] += __shfl_xor(sum[r], 8);
            if (hi8 == 0) {
                float4 o;
                o.x = sum[0]*0.1f; o.y = sum[1]*0.1f; o.z = sum[2]*0.1f; o.w = sum[3]*0.1f;
                *(float4*)(frow + co0) = o;
            }
        }
    }
}

// ---------------- kernel 2: fused mix + gelu + LN + proj (MFMA) ----------------
__global__ __launch_bounds__(512, 2) void mix_proj_kernel(
    const float* __restrict__ feat,
    const unsigned short* __restrict__ mixA, const float* __restrict__ bmixp,
    const float* __restrict__ lnwp, const float* __restrict__ lnbp,
    const unsigned short* __restrict__ projA, const float* __restrict__ proj_b,
    float* __restrict__ out)
{
    __shared__ __align__(16) unsigned short ulds[256*FT_STRIDE];
    unsigned short* fT = ulds;
    unsigned short* mT = ulds;

    const int t = threadIdx.x;
    const int wave = t >> 6, lane = t & 63;
    const int sL = lane & 15, gL = lane >> 4;
    const int n2 = blockIdx.x;
    const int b = n2 / P_, p = n2 % P_;

    const float* fbase = feat + (size_t)n2 * C_ * 256;
    for (int idx = t; idx < 129*256; idx += 512) {
        int c = idx >> 8, d = idx & 255;
        fT[d*FT_STRIDE + c] = f2bf(fbase[idx]);
    }
    for (int idx = t; idx < 256*31; idx += 512) {
        int d = idx / 31, c = 129 + idx % 31;
        fT[d*FT_STRIDE + c] = 0;
    }
    __syncthreads();

    f32x4 acc[9][2];
    #pragma unroll
    for (int mt = 0; mt < 9; ++mt)
        #pragma unroll
        for (int nt = 0; nt < 2; ++nt) acc[mt][nt] = (f32x4){0.f,0.f,0.f,0.f};

    #pragma unroll
    for (int kt = 0; kt < 5; ++kt) {
        short8 bb[2];
        #pragma unroll
        for (int nt = 0; nt < 2; ++nt) {
            int d = (wave*2 + nt)*16 + sL;
            bb[nt] = *(const short8*)&fT[d*FT_STRIDE + kt*32 + gL*8];
        }
        #pragma unroll
        for (int mt = 0; mt < 9; ++mt) {
            short8 a = *(const short8*)(mixA + (((kt*9 + mt)*64 + lane) << 3));
            #pragma unroll
            for (int nt = 0; nt < 2; ++nt)
                acc[mt][nt] = __builtin_amdgcn_mfma_f32_16x16x32_bf16(a, bb[nt], acc[mt][nt], 0, 0, 0);
        }
    }

    float sum[2] = {0.f, 0.f}, sq[2] = {0.f, 0.f};
    #pragma unroll
    for (int mt = 0; mt < 9; ++mt) {
        float4 bv = *(const float4*)(bmixp + mt*16 + gL*4);
        float bbr[4] = {bv.x, bv.y, bv.z, bv.w};
        #pragma unroll
        for (int nt = 0; nt < 2; ++nt) {
            #pragma unroll
            for (int r = 0; r < 4; ++r) {
                int o = mt*16 + gL*4 + r;
                float g = (o < 129) ? gelu_f(acc[mt][nt][r] + bbr[r]) : 0.f;
                acc[mt][nt][r] = g;
                sum[nt] += g;
                sq[nt]  += g*g;
            }
        }
    }
    float mu[2], rs[2];
    #pragma unroll
    for (int nt = 0; nt < 2; ++nt) {
        float s = sum[nt], q = sq[nt];
        s += __shfl_xor(s, 16); q += __shfl_xor(q, 16);
        s += __shfl_xor(s, 32); q += __shfl_xor(q, 32);
        mu[nt] = s * (1.f/129.f);
        float var = q * (1.f/129.f) - mu[nt]*mu[nt];
        rs[nt] = rsqrtf(var + 1e-5f);
    }

    __syncthreads();

    #pragma unroll
    for (int mt = 0; mt < 9; ++mt) {
        float4 lw = *(const float4*)(lnwp + mt*16 + gL*4);
        float4 lb = *(const float4*)(lnbp + mt*16 + gL*4);
        float lwr[4] = {lw.x, lw.y, lw.z, lw.w};
        float lbr[4] = {lb.x, lb.y, lb.z, lb.w};
        #pragma unroll
        for (int nt = 0; nt < 2; ++nt) {
            int d = (wave*2 + nt)*16 + sL;
            #pragma unroll
            for (int r = 0; r < 4; ++r) {
                int o = mt*16 + gL*4 + r;
                float y = (acc[mt][nt][r] - mu[nt]) * rs[nt] * lwr[r] + lbr[r];
                mT[o*MT_STRIDE + d] = f2bf(y);
            }
        }
    }
    __syncthreads();

    f32x4 pacc[2][9];
    #pragma unroll
    for (int mi = 0; mi < 2; ++mi)
        #pragma unroll
        for (int nt = 0; nt < 9; ++nt) pacc[mi][nt] = (f32x4){0.f,0.f,0.f,0.f};

    #pragma unroll
    for (int kt = 0; kt < 8; ++kt) {
        short8 a[2];
        #pragma unroll
        for (int mi = 0; mi < 2; ++mi)
            a[mi] = *(const short8*)(projA + (((kt*16 + wave*2 + mi)*64 + lane) << 3));
        #pragma unroll
        for (int nt = 0; nt < 9; ++nt) {
            short8 bb = *(const short8*)&mT[(nt*16 + sL)*MT_STRIDE + kt*32 + gL*8];
            #pragma unroll
            for (int mi = 0; mi < 2; ++mi)
                pacc[mi][nt] = __builtin_amdgcn_mfma_f32_16x16x32_bf16(a[mi], bb, pacc[mi][nt], 0, 0, 0);
        }
    }

    #pragma unroll
    for (int mi = 0; mi < 2; ++mi) {
        int e0 = (wave*2 + mi)*16 + gL*4;
        float4 pb4 = *(const float4*)(proj_b + e0);
        #pragma unroll
        for (int nt = 0; nt < 9; ++nt) {
            int c = nt*16 + sL;
            if (c < 129) {
                float4 o4;
                o4.x = pacc[mi][nt][0] + pb4.x;
                o4.y = pacc[mi][nt][1] + pb4.y;
                o4.z = pacc[mi][nt][2] + pb4.z;
                o4.w = pacc[mi][nt][3] + pb4.w;
                *(float4*)&out[(((size_t)(b*C_ + c)*P_) + p)*256 + e0] = o4;
            }
        }
    }
}

extern "C" void kernel_launch(void* const* d_in, const int* in_sizes, int n_in,
                              void* d_out, int out_size, void* d_ws, size_t ws_size,
                              hipStream_t stream) {
    (void)in_sizes; (void)n_in; (void)out_size; (void)ws_size;
    const float* x    = (const float*)d_in[0];
    const float* w1   = (const float*)d_in[1];
    const float* b1   = (const float*)d_in[2];
    const float* w2   = (const float*)d_in[3];
    const float* b2   = (const float*)d_in[4];
    const float* w3   = (const float*)d_in[5];
    const float* b3   = (const float*)d_in[6];
    const float* mixw = (const float*)d_in[7];
    const float* mixb = (const float*)d_in[8];
    const float* lnw  = (const float*)d_in[9];
    const float* lnb  = (const float*)d_in[10];
    const float* pw   = (const float*)d_in[11];
    const float* pb   = (const float*)d_in[12];
    float* out = (float*)d_out;
    float* ws  = (float*)d_ws;

    float* feat = ws;                                        // 63984*256 floats
    unsigned short* A2p  = (unsigned short*)(ws + 16379904); // 24576 u16
    unsigned short* A3p  = A2p + 24576;                      // 98304 u16
    unsigned short* mixA = A3p + 98304;                      // 23040 u16
    unsigned short* projA = mixA + 23040;                    // 65536 u16
    float* bmixp = (float*)(projA + 65536);                  // 144
    float* lnwp  = bmixp + 144;                              // 144
    float* lnbp  = lnwp + 144;                               // 144

    prep_kernel<<<256, 256, 0, stream>>>(w2, w3, mixw, pw, mixb, lnw, lnb,
                                         A2p, A3p, mixA, projA, bmixp, lnwp, lnbp);
    conv_mfma_kernel<<<NWG, 512, 0, stream>>>(x, w1, b1, A2p, b2, A3p, b3, feat);
    mix_proj_kernel<<<N2, 512, 0, stream>>>(feat, mixA, bmixp, lnwp, lnbp, projA, pb, out);
}

// Round 7
// 360.510 us; speedup vs baseline: 11.8011x; 1.0778x over previous
//
#include <hip/hip_runtime.h>

#define B_ 8
#define C_ 129
#define P_ 62
#define L_ 20
#define D_ 256
#define NSEG (B_*C_*P_)   /* 63984 */
#define N2   (B_*P_)      /* 496 */
#define SEGB 8
#define NWG  (NSEG/SEGB)  /* 7998 */

#define S1 1416   /* h1T per-seg stride in u16 */
#define S2 1544   /* hpT per-seg stride in u16 */

#define FT_STRIDE 168   /* fT [256 d][168] u16 */
#define MT_STRIDE 264   /* mT [144 o][264] u16 */

typedef short short8 __attribute__((ext_vector_type(8)));
typedef float f32x4  __attribute__((ext_vector_type(4)));

// Branchless erf-GELU via Abramowitz-Stegun 7.1.26 3-term (max |erf err| 2.5e-5;
// amplified through mix/LN/proj ~<0.01, well under threshold).
__device__ __forceinline__ float gelu_f(float x) {
    float u   = 0.70710678f * x;
    float au  = __builtin_fabsf(u);
    float den = fmaf(0.47047f, au, 1.0f);
    float t   = __builtin_amdgcn_rcpf(den);
    float q   = fmaf(0.7478556f, t, -0.0958798f);
    q = fmaf(q, t, 0.3480242f);
    float P  = q * t;
    float z  = (-1.4426950409f * au) * au;
    float e  = __builtin_amdgcn_exp2f(z);
    float ea = fmaf(-P, e, 1.0f);          // erf(|u|)
    float er = copysignf(ea, x);
    float hx = 0.5f * x;
    return fmaf(hx, er, hx);               // 0.5x(1+erf)
}
__device__ __forceinline__ unsigned short f2bf(float f) {   // scalar RNE (prep / mT only)
    unsigned u = __float_as_uint(f);
    u = u + 0x7FFFu + ((u >> 16) & 1u);
    return (unsigned short)(u >> 16);
}
// HW packed f32->bf16 RNE conversion: 1 inst / 2 values (replaces ~9-inst manual pair)
__device__ __forceinline__ unsigned cvt_pk_bf16(float lo, float hi) {
    unsigned r;
    asm("v_cvt_pk_bf16_f32 %0, %1, %2" : "=v"(r) : "v"(lo), "v"(hi));
    return r;
}

// ---------------- prep: pack all weights into MFMA fragment order ----------------
__global__ void prep_kernel(const float* __restrict__ w2, const float* __restrict__ w3,
                            const float* __restrict__ mw, const float* __restrict__ pw,
                            const float* __restrict__ mixb, const float* __restrict__ lnw,
                            const float* __restrict__ lnb,
                            unsigned short* __restrict__ A2p, unsigned short* __restrict__ A3p,
                            unsigned short* __restrict__ mixA, unsigned short* __restrict__ projA,
                            float* __restrict__ bmixp, float* __restrict__ lnwp,
                            float* __restrict__ lnbp) {
    int idx = blockIdx.x * blockDim.x + threadIdx.x;
    int stride = gridDim.x * blockDim.x;
    for (int f = idx; f < 6*8*64*8; f += stride) {
        int j = f & 7, ln = (f >> 3) & 63, mt = (f >> 9) & 7, kt = f >> 12;
        int co = mt*16 + (ln & 15);
        int k  = kt >> 1;
        int ci = (kt & 1)*32 + (ln >> 4)*8 + j;
        A2p[f] = f2bf(w2[(co*64 + ci)*3 + k]);
    }
    for (int f = idx; f < 12*16*64*8; f += stride) {
        int j = f & 7, ln = (f >> 3) & 63, mt = (f >> 9) & 15, kt = f >> 13;
        int co = mt*16 + (ln & 15);
        int k  = kt >> 2;
        int ci = (kt & 3)*32 + (ln >> 4)*8 + j;
        A3p[f] = f2bf(w3[(co*128 + ci)*3 + k]);
    }
    for (int f = idx; f < 5*9*64*8; f += stride) {
        int j = f & 7, ln = (f >> 3) & 63;
        int mt = (f >> 9) % 9, kt = (f >> 9) / 9;
        int o = mt*16 + (ln & 15);
        int c = kt*32 + (ln >> 4)*8 + j;
        mixA[f] = (o < 129 && c < 129) ? f2bf(mw[o*129 + c]) : (unsigned short)0;
    }
    for (int f = idx; f < 8*16*64*8; f += stride) {
        int j = f & 7, ln = (f >> 3) & 63, mt = (f >> 9) & 15, kt = f >> 13;
        int e = mt*16 + (ln & 15);
        int d = kt*32 + (ln >> 4)*8 + j;
        projA[f] = f2bf(pw[e*256 + d]);
    }
    for (int i = idx; i < 144; i += stride) {
        bmixp[i] = (i < 129) ? mixb[i] : 0.f;
        lnwp[i]  = (i < 129) ? lnw[i]  : 0.f;
        lnbp[i]  = (i < 129) ? lnb[i]  : 0.f;
    }
}

// ---------------- kernel 1: conv stack via MFMA, SEGB=8 (2 blocks/CU) ----------------
__global__ __launch_bounds__(512, 4) void conv_mfma_kernel(
    const float* __restrict__ x,
    const float* __restrict__ w1, const float* __restrict__ b1,
    const unsigned short* __restrict__ A2p, const float* __restrict__ b2,
    const unsigned short* __restrict__ A3p, const float* __restrict__ b3,
    unsigned short* __restrict__ feat)
{
    __shared__ __align__(16) unsigned short h1T[SEGB * S1]; // 22656 B
    __shared__ __align__(16) unsigned short hpT[SEGB * S2]; // 24704 B
    __shared__ float xs[SEGB][22];                          //   704 B

    const int t = threadIdx.x;
    const int wave = t >> 6, lane = t & 63;
    const int sL = lane & 15, gL = lane >> 4;
    const int seg8 = sL & 7, hi8 = sL >> 3;
    const int seg0 = blockIdx.x * SEGB;

    for (int idx = t; idx < SEGB*22; idx += 512) {
        int s = idx / 22, i = idx % 22;
        float v = 0.f;
        if (i >= 1 && i <= 20) v = x[(seg0 + s)*L_ + i - 1];
        xs[s][i] = v;
    }
    for (int idx = t; idx < SEGB*64; idx += 512) {
        int s = idx >> 6, ci = idx & 63;
        h1T[s*S1 + ci] = 0;
        h1T[s*S1 + 21*64 + ci] = 0;
    }
    for (int idx = t; idx < SEGB*128; idx += 512) {
        int s = idx >> 7, co = idx & 127;
        hpT[s*S2 + co] = 0;
        hpT[s*S2 + 11*128 + co] = 0;
    }
    __syncthreads();

    // conv1: wave w owns seg w; paired channels; cvt_pk + b32 writes
    {
        int seg = wave;
        int cp = (lane >> 1) & 31, ph = lane & 1;
        int ci0 = cp * 2;
        float wa0 = w1[ci0*3+0], wa1 = w1[ci0*3+1], wa2 = w1[ci0*3+2], ba = b1[ci0];
        float wb0 = w1[ci0*3+3], wb1 = w1[ci0*3+4], wb2 = w1[ci0*3+5], bb = b1[ci0+1];
        unsigned short* dst = &h1T[seg*S1 + ci0];
        #pragma unroll
        for (int i = 0; i < 10; ++i) {
            int l = ph*10 + i;
            float x0 = xs[seg][l], x1 = xs[seg][l+1], x2v = xs[seg][l+2];
            float va = fmaf(x0, wa0, fmaf(x1, wa1, fmaf(x2v, wa2, ba)));
            float vb = fmaf(x0, wb0, fmaf(x1, wb1, fmaf(x2v, wb2, bb)));
            *(unsigned*)(dst + (l+1)*64) = cvt_pk_bf16(gelu_f(va), gelu_f(vb));
        }
    }
    __syncthreads();

    // conv2 GEMM: M=128, N=160, K=192; gelu both parities, cross-lane max (exact order)
    {
        const int mh = wave & 3, ng = wave >> 2;
        f32x4 acc[2][5];
        #pragma unroll
        for (int mi = 0; mi < 2; ++mi)
            #pragma unroll
            for (int n = 0; n < 5; ++n) acc[mi][n] = (f32x4){0.f,0.f,0.f,0.f};

        const unsigned short* h1base = &h1T[seg8*S1 + (ng*10 + hi8)*64 + gL*8];
        #pragma unroll
        for (int h = 0; h < 2; ++h) {
            short8 br[11];
            #pragma unroll
            for (int r = 0; r < 11; ++r)
                br[r] = *(const short8*)(h1base + r*64 + h*32);
            #pragma unroll
            for (int k = 0; k < 3; ++k) {
                int kt = k*2 + h;
                short8 a0 = *(const short8*)(A2p + (((kt*8 + mh*2 + 0)*64 + lane) << 3));
                short8 a1 = *(const short8*)(A2p + (((kt*8 + mh*2 + 1)*64 + lane) << 3));
                #pragma unroll
                for (int n = 0; n < 5; ++n) {
                    acc[0][n] = __builtin_amdgcn_mfma_f32_16x16x32_bf16(a0, br[2*n+k], acc[0][n], 0, 0, 0);
                    acc[1][n] = __builtin_amdgcn_mfma_f32_16x16x32_bf16(a1, br[2*n+k], acc[1][n], 0, 0, 0);
                }
            }
        }
        #pragma unroll
        for (int mi = 0; mi < 2; ++mi) {
            int mt = mh*2 + mi;
            int co0 = mt*16 + gL*4;
            float4 bb = *(const float4*)(b2 + co0);
            float bbr[4] = {bb.x, bb.y, bb.z, bb.w};
            #pragma unroll
            for (int n = 0; n < 5; ++n) {
                int lp = ng*5 + n;
                float pv[4];
                #pragma unroll
                for (int r = 0; r < 4; ++r) {
                    float g = gelu_f(acc[mi][n][r] + bbr[r]);
                    pv[r] = fmaxf(g, __shfl_xor(g, 8));
                }
                if (hi8 == 0) {
                    uint2 pk;
                    pk.x = cvt_pk_bf16(pv[0], pv[1]);
                    pk.y = cvt_pk_bf16(pv[2], pv[3]);
                    *(uint2*)&hpT[seg8*S2 + (lp+1)*128 + co0] = pk;
                }
            }
        }
    }
    __syncthreads();

    // conv3 GEMM: M=256, N=80, K=384; gelu + mean; bf16 feat output
    {
        f32x4 acc[2][5];
        #pragma unroll
        for (int mi = 0; mi < 2; ++mi)
            #pragma unroll
            for (int n = 0; n < 5; ++n) acc[mi][n] = (f32x4){0.f,0.f,0.f,0.f};

        const unsigned short* hpbase = &hpT[seg8*S2 + hi8*128 + gL*8];
        #pragma unroll
        for (int q = 0; q < 4; ++q) {
            short8 br[11];
            #pragma unroll
            for (int r = 0; r < 11; ++r)
                br[r] = *(const short8*)(hpbase + r*128 + q*32);
            #pragma unroll
            for (int k = 0; k < 3; ++k) {
                int kt = k*4 + q;
                short8 a0 = *(const short8*)(A3p + (((kt*16 + wave*2 + 0)*64 + lane) << 3));
                short8 a1 = *(const short8*)(A3p + (((kt*16 + wave*2 + 1)*64 + lane) << 3));
                #pragma unroll
                for (int n = 0; n < 5; ++n) {
                    acc[0][n] = __builtin_amdgcn_mfma_f32_16x16x32_bf16(a0, br[2*n+k], acc[0][n], 0, 0, 0);
                    acc[1][n] = __builtin_amdgcn_mfma_f32_16x16x32_bf16(a1, br[2*n+k], acc[1][n], 0, 0, 0);
                }
            }
        }
        int seg = seg0 + seg8;
        int bI = seg / (C_*P_);
        int rem = seg % (C_*P_);
        int c = rem / P_, p = rem % P_;
        unsigned short* frow = feat + (((size_t)(bI*P_ + p)*C_ + c) << 8);
        #pragma unroll
        for (int mi = 0; mi < 2; ++mi) {
            int co0 = (wave*2 + mi)*16 + gL*4;
            float4 bv = *(const float4*)(b3 + co0);
            float bbr[4] = {bv.x, bv.y, bv.z, bv.w};
            float sum[4] = {0.f, 0.f, 0.f, 0.f};
            #pragma unroll
            for (int n = 0; n < 5; ++n)
                #pragma unroll
                for (int r = 0; r < 4; ++r)
                    sum[r] += gelu_f(acc[mi][n][r] + bbr[r]);
            #pragma unroll
            for (int r = 0; r < 4; ++r)
                sum[r] += __shfl_xor(sum[r], 8);
            if (hi8 == 0) {
                uint2 o;
                o.x = cvt_pk_bf16(sum[0]*0.1f, sum[1]*0.1f);
                o.y = cvt_pk_bf16(sum[2]*0.1f, sum[3]*0.1f);
                *(uint2*)(frow + co0) = o;
            }
        }
    }
}

// ---------------- kernel 2: fused mix + gelu + LN + proj (MFMA) ----------------
__global__ __launch_bounds__(512, 2) void mix_proj_kernel(
    const unsigned short* __restrict__ feat,
    const unsigned short* __restrict__ mixA, const float* __restrict__ bmixp,
    const float* __restrict__ lnwp, const float* __restrict__ lnbp,
    const unsigned short* __restrict__ projA, const float* __restrict__ proj_b,
    float* __restrict__ out)
{
    __shared__ __align__(16) unsigned short ulds[256*FT_STRIDE];
    unsigned short* fT = ulds;
    unsigned short* mT = ulds;

    const int t = threadIdx.x;
    const int wave = t >> 6, lane = t & 63;
    const int sL = lane & 15, gL = lane >> 4;
    const int n2 = blockIdx.x;
    const int b = n2 / P_, p = n2 % P_;

    // stage fT[d][c] from bf16 feat (pure copy; pairs of d per u32)
    const unsigned* fbase32 = (const unsigned*)(feat + (size_t)n2 * C_ * 256);
    for (int idx = t; idx < 129*128; idx += 512) {
        int c = idx >> 7, q = idx & 127;
        unsigned v = fbase32[idx];
        int d0 = q * 2;
        fT[d0*FT_STRIDE + c]     = (unsigned short)(v & 0xFFFFu);
        fT[(d0+1)*FT_STRIDE + c] = (unsigned short)(v >> 16);
    }
    for (int idx = t; idx < 256*31; idx += 512) {
        int d = idx / 31, c = 129 + idx % 31;
        fT[d*FT_STRIDE + c] = 0;
    }
    __syncthreads();

    f32x4 acc[9][2];
    #pragma unroll
    for (int mt = 0; mt < 9; ++mt)
        #pragma unroll
        for (int nt = 0; nt < 2; ++nt) acc[mt][nt] = (f32x4){0.f,0.f,0.f,0.f};

    #pragma unroll
    for (int kt = 0; kt < 5; ++kt) {
        short8 bb[2];
        #pragma unroll
        for (int nt = 0; nt < 2; ++nt) {
            int d = (wave*2 + nt)*16 + sL;
            bb[nt] = *(const short8*)&fT[d*FT_STRIDE + kt*32 + gL*8];
        }
        #pragma unroll
        for (int mt = 0; mt < 9; ++mt) {
            short8 a = *(const short8*)(mixA + (((kt*9 + mt)*64 + lane) << 3));
            #pragma unroll
            for (int nt = 0; nt < 2; ++nt)
                acc[mt][nt] = __builtin_amdgcn_mfma_f32_16x16x32_bf16(a, bb[nt], acc[mt][nt], 0, 0, 0);
        }
    }

    float sum[2] = {0.f, 0.f}, sq[2] = {0.f, 0.f};
    #pragma unroll
    for (int mt = 0; mt < 9; ++mt) {
        float4 bv = *(const float4*)(bmixp + mt*16 + gL*4);
        float bbr[4] = {bv.x, bv.y, bv.z, bv.w};
        #pragma unroll
        for (int nt = 0; nt < 2; ++nt) {
            #pragma unroll
            for (int r = 0; r < 4; ++r) {
                int o = mt*16 + gL*4 + r;
                float g = (o < 129) ? gelu_f(acc[mt][nt][r] + bbr[r]) : 0.f;
                acc[mt][nt][r] = g;
                sum[nt] += g;
                sq[nt]  += g*g;
            }
        }
    }
    float mu[2], rs[2];
    #pragma unroll
    for (int nt = 0; nt < 2; ++nt) {
        float s = sum[nt], q = sq[nt];
        s += __shfl_xor(s, 16); q += __shfl_xor(q, 16);
        s += __shfl_xor(s, 32); q += __shfl_xor(q, 32);
        mu[nt] = s * (1.f/129.f);
        float var = q * (1.f/129.f) - mu[nt]*mu[nt];
        rs[nt] = rsqrtf(var + 1e-5f);
    }

    __syncthreads();

    #pragma unroll
    for (int mt = 0; mt < 9; ++mt) {
        float4 lw = *(const float4*)(lnwp + mt*16 + gL*4);
        float4 lb = *(const float4*)(lnbp + mt*16 + gL*4);
        float lwr[4] = {lw.x, lw.y, lw.z, lw.w};
        float lbr[4] = {lb.x, lb.y, lb.z, lb.w};
        #pragma unroll
        for (int nt = 0; nt < 2; ++nt) {
            int d = (wave*2 + nt)*16 + sL;
            #pragma unroll
            for (int r = 0; r < 4; ++r) {
                int o = mt*16 + gL*4 + r;
                float y = (acc[mt][nt][r] - mu[nt]) * rs[nt] * lwr[r] + lbr[r];
                mT[o*MT_STRIDE + d] = f2bf(y);
            }
        }
    }
    __syncthreads();

    f32x4 pacc[2][9];
    #pragma unroll
    for (int mi = 0; mi < 2; ++mi)
        #pragma unroll
        for (int nt = 0; nt < 9; ++nt) pacc[mi][nt] = (f32x4){0.f,0.f,0.f,0.f};

    #pragma unroll
    for (int kt = 0; kt < 8; ++kt) {
        short8 a[2];
        #pragma unroll
        for (int mi = 0; mi < 2; ++mi)
            a[mi] = *(const short8*)(projA + (((kt*16 + wave*2 + mi)*64 + lane) << 3));
        #pragma unroll
        for (int nt = 0; nt < 9; ++nt) {
            short8 bb = *(const short8*)&mT[(nt*16 + sL)*MT_STRIDE + kt*32 + gL*8];
            #pragma unroll
            for (int mi = 0; mi < 2; ++mi)
                pacc[mi][nt] = __builtin_amdgcn_mfma_f32_16x16x32_bf16(a[mi], bb, pacc[mi][nt], 0, 0, 0);
        }
    }

    #pragma unroll
    for (int mi = 0; mi < 2; ++mi) {
        int e0 = (wave*2 + mi)*16 + gL*4;
        float4 pb4 = *(const float4*)(proj_b + e0);
        #pragma unroll
        for (int nt = 0; nt < 9; ++nt) {
            int c = nt*16 + sL;
            if (c < 129) {
                float4 o4;
                o4.x = pacc[mi][nt][0] + pb4.x;
                o4.y = pacc[mi][nt][1] + pb4.y;
                o4.z = pacc[mi][nt][2] + pb4.z;
                o4.w = pacc[mi][nt][3] + pb4.w;
                *(float4*)&out[(((size_t)(b*C_ + c)*P_) + p)*256 + e0] = o4;
            }
        }
    }
}

extern "C" void kernel_launch(void* const* d_in, const int* in_sizes, int n_in,
                              void* d_out, int out_size, void* d_ws, size_t ws_size,
                              hipStream_t stream) {
    (void)in_sizes; (void)n_in; (void)out_size; (void)ws_size;
    const float* x    = (const float*)d_in[0];
    const float* w1   = (const float*)d_in[1];
    const float* b1   = (const float*)d_in[2];
    const float* w2   = (const float*)d_in[3];
    const float* b2   = (const float*)d_in[4];
    const float* w3   = (const float*)d_in[5];
    const float* b3   = (const float*)d_in[6];
    const float* mixw = (const float*)d_in[7];
    const float* mixb = (const float*)d_in[8];
    const float* lnw  = (const float*)d_in[9];
    const float* lnb  = (const float*)d_in[10];
    const float* pw   = (const float*)d_in[11];
    const float* pb   = (const float*)d_in[12];
    float* out = (float*)d_out;
    float* ws  = (float*)d_ws;

    unsigned short* feat = (unsigned short*)ws;              // 63984*256 bf16 (32.7 MB)
    unsigned short* A2p  = (unsigned short*)(ws + 16379904); // 24576 u16
    unsigned short* A3p  = A2p + 24576;                      // 98304 u16
    unsigned short* mixA = A3p + 98304;                      // 23040 u16
    unsigned short* projA = mixA + 23040;                    // 65536 u16
    float* bmixp = (float*)(projA + 65536);                  // 144
    float* lnwp  = bmixp + 144;                              // 144
    float* lnbp  = lnwp + 144;                               // 144

    prep_kernel<<<256, 256, 0, stream>>>(w2, w3, mixw, pw, mixb, lnw, lnb,
                                         A2p, A3p, mixA, projA, bmixp, lnwp, lnbp);
    conv_mfma_kernel<<<NWG, 512, 0, stream>>>(x, w1, b1, A2p, b2, A3p, b3, feat);
    mix_proj_kernel<<<N2, 512, 0, stream>>>(feat, mixA, bmixp, lnwp, lnbp, projA, pb, out);
}

// Round 8
// 352.157 us; speedup vs baseline: 12.0810x; 1.0237x over previous
//
#include <hip/hip_runtime.h>

#define B_ 8
#define C_ 129
#define P_ 62
#define L_ 20
#define D_ 256
#define NSEG (B_*C_*P_)   /* 63984 */
#define N2   (B_*P_)      /* 496 */
#define SEGB 8
#define NWG  (NSEG/SEGB)  /* 7998 */

#define S1 1416   /* h1T per-seg stride in u16 */
#define S2 1544   /* hpT per-seg stride in u16 */

#define FT_STRIDE 168   /* fT [256 d][168] u16 */
#define MT_STRIDE 264   /* mT [144 o][264] u16 */

typedef short short8 __attribute__((ext_vector_type(8)));
typedef float f32x4  __attribute__((ext_vector_type(4)));

// Branchless erf-GELU via Abramowitz-Stegun 7.1.26 3-term (max |erf err| 2.5e-5).
__device__ __forceinline__ float gelu_f(float x) {
    float u   = 0.70710678f * x;
    float au  = __builtin_fabsf(u);
    float den = fmaf(0.47047f, au, 1.0f);
    float t   = __builtin_amdgcn_rcpf(den);
    float q   = fmaf(0.7478556f, t, -0.0958798f);
    q = fmaf(q, t, 0.3480242f);
    float P  = q * t;
    float z  = (-1.4426950409f * au) * au;
    float e  = __builtin_amdgcn_exp2f(z);
    float ea = fmaf(-P, e, 1.0f);          // erf(|u|)
    float er = copysignf(ea, x);
    float hx = 0.5f * x;
    return fmaf(hx, er, hx);               // 0.5x(1+erf)
}
__device__ __forceinline__ unsigned short f2bf(float f) {   // scalar RNE (prep / mT only)
    unsigned u = __float_as_uint(f);
    u = u + 0x7FFFu + ((u >> 16) & 1u);
    return (unsigned short)(u >> 16);
}
// HW packed f32->bf16 RNE conversion
__device__ __forceinline__ unsigned cvt_pk_bf16(float lo, float hi) {
    unsigned r;
    asm("v_cvt_pk_bf16_f32 %0, %1, %2" : "=v"(r) : "v"(lo), "v"(hi));
    return r;
}

// ---------------- prep: pack all weights into MFMA fragment order ----------------
__global__ void prep_kernel(const float* __restrict__ w2, const float* __restrict__ w3,
                            const float* __restrict__ mw, const float* __restrict__ pw,
                            const float* __restrict__ mixb, const float* __restrict__ lnw,
                            const float* __restrict__ lnb,
                            unsigned short* __restrict__ A2p, unsigned short* __restrict__ A3p,
                            unsigned short* __restrict__ mixA, unsigned short* __restrict__ projA,
                            float* __restrict__ bmixp, float* __restrict__ lnwp,
                            float* __restrict__ lnbp) {
    int idx = blockIdx.x * blockDim.x + threadIdx.x;
    int stride = gridDim.x * blockDim.x;
    for (int f = idx; f < 6*8*64*8; f += stride) {
        int j = f & 7, ln = (f >> 3) & 63, mt = (f >> 9) & 7, kt = f >> 12;
        int co = mt*16 + (ln & 15);
        int k  = kt >> 1;
        int ci = (kt & 1)*32 + (ln >> 4)*8 + j;
        A2p[f] = f2bf(w2[(co*64 + ci)*3 + k]);
    }
    for (int f = idx; f < 12*16*64*8; f += stride) {
        int j = f & 7, ln = (f >> 3) & 63, mt = (f >> 9) & 15, kt = f >> 13;
        int co = mt*16 + (ln & 15);
        int k  = kt >> 2;
        int ci = (kt & 3)*32 + (ln >> 4)*8 + j;
        A3p[f] = f2bf(w3[(co*128 + ci)*3 + k]);
    }
    for (int f = idx; f < 5*9*64*8; f += stride) {
        int j = f & 7, ln = (f >> 3) & 63;
        int mt = (f >> 9) % 9, kt = (f >> 9) / 9;
        int o = mt*16 + (ln & 15);
        int c = kt*32 + (ln >> 4)*8 + j;
        mixA[f] = (o < 129 && c < 129) ? f2bf(mw[o*129 + c]) : (unsigned short)0;
    }
    for (int f = idx; f < 8*16*64*8; f += stride) {
        int j = f & 7, ln = (f >> 3) & 63, mt = (f >> 9) & 15, kt = f >> 13;
        int e = mt*16 + (ln & 15);
        int d = kt*32 + (ln >> 4)*8 + j;
        projA[f] = f2bf(pw[e*256 + d]);
    }
    for (int i = idx; i < 144; i += stride) {
        bmixp[i] = (i < 129) ? mixb[i] : 0.f;
        lnwp[i]  = (i < 129) ? lnw[i]  : 0.f;
        lnbp[i]  = (i < 129) ? lnb[i]  : 0.f;
    }
}

// ---------------- kernel 1: conv stack via MFMA, SEGB=8 ----------------
// __launch_bounds__(512,2): VGPR cap 256 (expect ~96-128) so br[] cache + acc live
// in registers; (512,4)'s 64-VGPR clamp forced compiler re-reads (round-7 lesson).
__global__ __launch_bounds__(512, 2) void conv_mfma_kernel(
    const float* __restrict__ x,
    const float* __restrict__ w1, const float* __restrict__ b1,
    const unsigned short* __restrict__ A2p, const float* __restrict__ b2,
    const unsigned short* __restrict__ A3p, const float* __restrict__ b3,
    unsigned short* __restrict__ feat)
{
    __shared__ __align__(16) unsigned short h1T[SEGB * S1]; // 22656 B
    __shared__ __align__(16) unsigned short hpT[SEGB * S2]; // 24704 B
    __shared__ float xs[SEGB][22];                          //   704 B

    const int t = threadIdx.x;
    const int wave = t >> 6, lane = t & 63;
    const int sL = lane & 15, gL = lane >> 4;
    const int seg8 = sL & 7, hi8 = sL >> 3;
    const int seg0 = blockIdx.x * SEGB;

    for (int idx = t; idx < SEGB*22; idx += 512) {
        int s = idx / 22, i = idx % 22;
        float v = 0.f;
        if (i >= 1 && i <= 20) v = x[(seg0 + s)*L_ + i - 1];
        xs[s][i] = v;
    }
    for (int idx = t; idx < SEGB*64; idx += 512) {
        int s = idx >> 6, ci = idx & 63;
        h1T[s*S1 + ci] = 0;
        h1T[s*S1 + 21*64 + ci] = 0;
    }
    for (int idx = t; idx < SEGB*128; idx += 512) {
        int s = idx >> 7, co = idx & 127;
        hpT[s*S2 + co] = 0;
        hpT[s*S2 + 11*128 + co] = 0;
    }
    __syncthreads();

    // conv1: wave w owns seg w; paired channels; cvt_pk + b32 writes
    {
        int seg = wave;
        int cp = (lane >> 1) & 31, ph = lane & 1;
        int ci0 = cp * 2;
        float wa0 = w1[ci0*3+0], wa1 = w1[ci0*3+1], wa2 = w1[ci0*3+2], ba = b1[ci0];
        float wb0 = w1[ci0*3+3], wb1 = w1[ci0*3+4], wb2 = w1[ci0*3+5], bb = b1[ci0+1];
        unsigned short* dst = &h1T[seg*S1 + ci0];
        #pragma unroll
        for (int i = 0; i < 10; ++i) {
            int l = ph*10 + i;
            float x0 = xs[seg][l], x1 = xs[seg][l+1], x2v = xs[seg][l+2];
            float va = fmaf(x0, wa0, fmaf(x1, wa1, fmaf(x2v, wa2, ba)));
            float vb = fmaf(x0, wb0, fmaf(x1, wb1, fmaf(x2v, wb2, bb)));
            *(unsigned*)(dst + (l+1)*64) = cvt_pk_bf16(gelu_f(va), gelu_f(vb));
        }
    }
    __syncthreads();

    // conv2 GEMM: M=128, N=160, K=192; bias preloaded into accumulators
    {
        const int mh = wave & 3, ng = wave >> 2;
        f32x4 bias[2];
        #pragma unroll
        for (int mi = 0; mi < 2; ++mi) {
            float4 bb = *(const float4*)(b2 + (mh*2 + mi)*16 + gL*4);
            bias[mi] = (f32x4){bb.x, bb.y, bb.z, bb.w};
        }
        f32x4 acc[2][5];
        #pragma unroll
        for (int mi = 0; mi < 2; ++mi)
            #pragma unroll
            for (int n = 0; n < 5; ++n) acc[mi][n] = bias[mi];

        const unsigned short* h1base = &h1T[seg8*S1 + (ng*10 + hi8)*64 + gL*8];
        #pragma unroll
        for (int h = 0; h < 2; ++h) {
            short8 br[11];
            #pragma unroll
            for (int r = 0; r < 11; ++r)
                br[r] = *(const short8*)(h1base + r*64 + h*32);
            #pragma unroll
            for (int k = 0; k < 3; ++k) {
                int kt = k*2 + h;
                short8 a0 = *(const short8*)(A2p + (((kt*8 + mh*2 + 0)*64 + lane) << 3));
                short8 a1 = *(const short8*)(A2p + (((kt*8 + mh*2 + 1)*64 + lane) << 3));
                #pragma unroll
                for (int n = 0; n < 5; ++n) {
                    acc[0][n] = __builtin_amdgcn_mfma_f32_16x16x32_bf16(a0, br[2*n+k], acc[0][n], 0, 0, 0);
                    acc[1][n] = __builtin_amdgcn_mfma_f32_16x16x32_bf16(a1, br[2*n+k], acc[1][n], 0, 0, 0);
                }
            }
        }
        #pragma unroll
        for (int mi = 0; mi < 2; ++mi) {
            int mt = mh*2 + mi;
            int co0 = mt*16 + gL*4;
            #pragma unroll
            for (int n = 0; n < 5; ++n) {
                int lp = ng*5 + n;
                float pv[4];
                #pragma unroll
                for (int r = 0; r < 4; ++r) {
                    float g = gelu_f(acc[mi][n][r]);
                    pv[r] = fmaxf(g, __shfl_xor(g, 8));
                }
                if (hi8 == 0) {
                    uint2 pk;
                    pk.x = cvt_pk_bf16(pv[0], pv[1]);
                    pk.y = cvt_pk_bf16(pv[2], pv[3]);
                    *(uint2*)&hpT[seg8*S2 + (lp+1)*128 + co0] = pk;
                }
            }
        }
    }
    __syncthreads();

    // conv3 GEMM: M=256, N=80, K=384; bias in acc; gelu + mean; bf16 feat output
    {
        f32x4 bias[2];
        #pragma unroll
        for (int mi = 0; mi < 2; ++mi) {
            float4 bv = *(const float4*)(b3 + (wave*2 + mi)*16 + gL*4);
            bias[mi] = (f32x4){bv.x, bv.y, bv.z, bv.w};
        }
        f32x4 acc[2][5];
        #pragma unroll
        for (int mi = 0; mi < 2; ++mi)
            #pragma unroll
            for (int n = 0; n < 5; ++n) acc[mi][n] = bias[mi];

        const unsigned short* hpbase = &hpT[seg8*S2 + hi8*128 + gL*8];
        #pragma unroll
        for (int q = 0; q < 4; ++q) {
            short8 br[11];
            #pragma unroll
            for (int r = 0; r < 11; ++r)
                br[r] = *(const short8*)(hpbase + r*128 + q*32);
            #pragma unroll
            for (int k = 0; k < 3; ++k) {
                int kt = k*4 + q;
                short8 a0 = *(const short8*)(A3p + (((kt*16 + wave*2 + 0)*64 + lane) << 3));
                short8 a1 = *(const short8*)(A3p + (((kt*16 + wave*2 + 1)*64 + lane) << 3));
                #pragma unroll
                for (int n = 0; n < 5; ++n) {
                    acc[0][n] = __builtin_amdgcn_mfma_f32_16x16x32_bf16(a0, br[2*n+k], acc[0][n], 0, 0, 0);
                    acc[1][n] = __builtin_amdgcn_mfma_f32_16x16x32_bf16(a1, br[2*n+k], acc[1][n], 0, 0, 0);
                }
            }
        }
        int seg = seg0 + seg8;
        int bI = seg / (C_*P_);
        int rem = seg % (C_*P_);
        int c = rem / P_, p = rem % P_;
        unsigned short* frow = feat + (((size_t)(bI*P_ + p)*C_ + c) << 8);
        #pragma unroll
        for (int mi = 0; mi < 2; ++mi) {
            int co0 = (wave*2 + mi)*16 + gL*4;
            float sum[4] = {0.f, 0.f, 0.f, 0.f};
            #pragma unroll
            for (int n = 0; n < 5; ++n)
                #pragma unroll
                for (int r = 0; r < 4; ++r)
                    sum[r] += gelu_f(acc[mi][n][r]);
            #pragma unroll
            for (int r = 0; r < 4; ++r)
                sum[r] += __shfl_xor(sum[r], 8);
            if (hi8 == 0) {
                uint2 o;
                o.x = cvt_pk_bf16(sum[0]*0.1f, sum[1]*0.1f);
                o.y = cvt_pk_bf16(sum[2]*0.1f, sum[3]*0.1f);
                *(uint2*)(frow + co0) = o;
            }
        }
    }
}

// ---------------- kernel 2: fused mix + gelu + LN + proj (MFMA) ----------------
__global__ __launch_bounds__(512, 2) void mix_proj_kernel(
    const unsigned short* __restrict__ feat,
    const unsigned short* __restrict__ mixA, const float* __restrict__ bmixp,
    const float* __restrict__ lnwp, const float* __restrict__ lnbp,
    const unsigned short* __restrict__ projA, const float* __restrict__ proj_b,
    float* __restrict__ out)
{
    __shared__ __align__(16) unsigned short ulds[256*FT_STRIDE];
    unsigned short* fT = ulds;
    unsigned short* mT = ulds;

    const int t = threadIdx.x;
    const int wave = t >> 6, lane = t & 63;
    const int sL = lane & 15, gL = lane >> 4;
    const int n2 = blockIdx.x;
    const int b = n2 / P_, p = n2 % P_;

    // stage fT[d][c] from bf16 feat (pure copy; pairs of d per u32)
    const unsigned* fbase32 = (const unsigned*)(feat + (size_t)n2 * C_ * 256);
    for (int idx = t; idx < 129*128; idx += 512) {
        int c = idx >> 7, q = idx & 127;
        unsigned v = fbase32[idx];
        int d0 = q * 2;
        fT[d0*FT_STRIDE + c]     = (unsigned short)(v & 0xFFFFu);
        fT[(d0+1)*FT_STRIDE + c] = (unsigned short)(v >> 16);
    }
    for (int idx = t; idx < 256*31; idx += 512) {
        int d = idx / 31, c = 129 + idx % 31;
        fT[d*FT_STRIDE + c] = 0;
    }
    __syncthreads();

    // mix GEMM: bias preloaded into accumulators (zero rows for o>=129)
    f32x4 acc[9][2];
    #pragma unroll
    for (int mt = 0; mt < 9; ++mt) {
        float4 bv = *(const float4*)(bmixp + mt*16 + gL*4);
        f32x4 bi = (f32x4){bv.x, bv.y, bv.z, bv.w};
        acc[mt][0] = bi;
        acc[mt][1] = bi;
    }

    #pragma unroll
    for (int kt = 0; kt < 5; ++kt) {
        short8 bb[2];
        #pragma unroll
        for (int nt = 0; nt < 2; ++nt) {
            int d = (wave*2 + nt)*16 + sL;
            bb[nt] = *(const short8*)&fT[d*FT_STRIDE + kt*32 + gL*8];
        }
        #pragma unroll
        for (int mt = 0; mt < 9; ++mt) {
            short8 a = *(const short8*)(mixA + (((kt*9 + mt)*64 + lane) << 3));
            #pragma unroll
            for (int nt = 0; nt < 2; ++nt)
                acc[mt][nt] = __builtin_amdgcn_mfma_f32_16x16x32_bf16(a, bb[nt], acc[mt][nt], 0, 0, 0);
        }
    }

    // gelu + LN stats (acc=0 for o>=129 -> gelu(0)=0 exactly, no mask needed)
    float sum[2] = {0.f, 0.f}, sq[2] = {0.f, 0.f};
    #pragma unroll
    for (int mt = 0; mt < 9; ++mt) {
        #pragma unroll
        for (int nt = 0; nt < 2; ++nt) {
            #pragma unroll
            for (int r = 0; r < 4; ++r) {
                float g = gelu_f(acc[mt][nt][r]);
                acc[mt][nt][r] = g;
                sum[nt] += g;
                sq[nt]  += g*g;
            }
        }
    }
    float mu[2], rs[2];
    #pragma unroll
    for (int nt = 0; nt < 2; ++nt) {
        float s = sum[nt], q = sq[nt];
        s += __shfl_xor(s, 16); q += __shfl_xor(q, 16);
        s += __shfl_xor(s, 32); q += __shfl_xor(q, 32);
        mu[nt] = s * (1.f/129.f);
        float var = q * (1.f/129.f) - mu[nt]*mu[nt];
        rs[nt] = rsqrtf(var + 1e-5f);
    }

    __syncthreads();

    #pragma unroll
    for (int mt = 0; mt < 9; ++mt) {
        float4 lw = *(const float4*)(lnwp + mt*16 + gL*4);
        float4 lb = *(const float4*)(lnbp + mt*16 + gL*4);
        float lwr[4] = {lw.x, lw.y, lw.z, lw.w};
        float lbr[4] = {lb.x, lb.y, lb.z, lb.w};
        #pragma unroll
        for (int nt = 0; nt < 2; ++nt) {
            int d = (wave*2 + nt)*16 + sL;
            #pragma unroll
            for (int r = 0; r < 4; ++r) {
                int o = mt*16 + gL*4 + r;
                float y = (acc[mt][nt][r] - mu[nt]) * rs[nt] * lwr[r] + lbr[r];
                mT[o*MT_STRIDE + d] = f2bf(y);
            }
        }
    }
    __syncthreads();

    f32x4 pacc[2][9];
    #pragma unroll
    for (int mi = 0; mi < 2; ++mi)
        #pragma unroll
        for (int nt = 0; nt < 9; ++nt) pacc[mi][nt] = (f32x4){0.f,0.f,0.f,0.f};

    #pragma unroll
    for (int kt = 0; kt < 8; ++kt) {
        short8 a[2];
        #pragma unroll
        for (int mi = 0; mi < 2; ++mi)
            a[mi] = *(const short8*)(projA + (((kt*16 + wave*2 + mi)*64 + lane) << 3));
        #pragma unroll
        for (int nt = 0; nt < 9; ++nt) {
            short8 bb = *(const short8*)&mT[(nt*16 + sL)*MT_STRIDE + kt*32 + gL*8];
            #pragma unroll
            for (int mi = 0; mi < 2; ++mi)
                pacc[mi][nt] = __builtin_amdgcn_mfma_f32_16x16x32_bf16(a[mi], bb, pacc[mi][nt], 0, 0, 0);
        }
    }

    #pragma unroll
    for (int mi = 0; mi < 2; ++mi) {
        int e0 = (wave*2 + mi)*16 + gL*4;
        float4 pb4 = *(const float4*)(proj_b + e0);
        #pragma unroll
        for (int nt = 0; nt < 9; ++nt) {
            int c = nt*16 + sL;
            if (c < 129) {
                float4 o4;
                o4.x = pacc[mi][nt][0] + pb4.x;
                o4.y = pacc[mi][nt][1] + pb4.y;
                o4.z = pacc[mi][nt][2] + pb4.z;
                o4.w = pacc[mi][nt][3] + pb4.w;
                *(float4*)&out[(((size_t)(b*C_ + c)*P_) + p)*256 + e0] = o4;
            }
        }
    }
}

extern "C" void kernel_launch(void* const* d_in, const int* in_sizes, int n_in,
                              void* d_out, int out_size, void* d_ws, size_t ws_size,
                              hipStream_t stream) {
    (void)in_sizes; (void)n_in; (void)out_size; (void)ws_size;
    const float* x    = (const float*)d_in[0];
    const float* w1   = (const float*)d_in[1];
    const float* b1   = (const float*)d_in[2];
    const float* w2   = (const float*)d_in[3];
    const float* b2   = (const float*)d_in[4];
    const float* w3   = (const float*)d_in[5];
    const float* b3   = (const float*)d_in[6];
    const float* mixw = (const float*)d_in[7];
    const float* mixb = (const float*)d_in[8];
    const float* lnw  = (const float*)d_in[9];
    const float* lnb  = (const float*)d_in[10];
    const float* pw   = (const float*)d_in[11];
    const float* pb   = (const float*)d_in[12];
    float* out = (float*)d_out;
    float* ws  = (float*)d_ws;

    unsigned short* feat = (unsigned short*)ws;              // 63984*256 bf16 (32.7 MB)
    unsigned short* A2p  = (unsigned short*)(ws + 16379904); // 24576 u16
    unsigned short* A3p  = A2p + 24576;                      // 98304 u16
    unsigned short* mixA = A3p + 98304;                      // 23040 u16
    unsigned short* projA = mixA + 23040;                    // 65536 u16
    float* bmixp = (float*)(projA + 65536);                  // 144
    float* lnwp  = bmixp + 144;                              // 144
    float* lnbp  = lnwp + 144;                               // 144

    prep_kernel<<<256, 256, 0, stream>>>(w2, w3, mixw, pw, mixb, lnw, lnb,
                                         A2p, A3p, mixA, projA, bmixp, lnwp, lnbp);
    conv_mfma_kernel<<<NWG, 512, 0, stream>>>(x, w1, b1, A2p, b2, A3p, b3, feat);
    mix_proj_kernel<<<N2, 512, 0, stream>>>(feat, mixA, bmixp, lnwp, lnbp, projA, pb, out);
}